// Round 15
// baseline (292.106 us; speedup 1.0000x reference)
//
#include <hip/hip_runtime.h>
#include <stdint.h>

// Pipeline: cvt(fp32->bf16, + RoPE tables region)
//   -> gemm_qk: x@[Wq;Wk] (N=4096), 256^2 tiles, grid 256 = one full round
//   -> gemm_v : x@Wv (N=2048), 128x256 tiles, grid 256 = one round
//   -> rope(Q,K)
//   -> attn_fwd R15: QBLK=128, 4 waves x 32 q-rows (2 Q-frags in regs -> each K/V frag
//      read feeds 2 MFMA, halving the LDS-read critical path), pair (p,15-p) uniform 34
//      tiles, grid (bh=32, pair=8)=256 XCD-aligned, counted-vmcnt dbuf, defer-max.
//   -> gemm_bt out-proj (128^2).

#define SCALE_Q 0.08838834764831845f

typedef short bf16x8 __attribute__((ext_vector_type(8)));
typedef float f32x4 __attribute__((ext_vector_type(4)));
typedef unsigned short u16x4v __attribute__((ext_vector_type(4)));
typedef unsigned short u16x8v __attribute__((ext_vector_type(8)));

__device__ __forceinline__ unsigned short f2bf(float f) {
  unsigned u = __float_as_uint(f);
  return (unsigned short)((u + 0x7FFFu + ((u >> 16) & 1u)) >> 16);  // RNE
}
__device__ __forceinline__ float bf2f(unsigned short h) {
  return __uint_as_float(((unsigned)h) << 16);
}
__device__ __forceinline__ void gld16(void* lds, const void* g) {
  __builtin_amdgcn_global_load_lds(
      (const __attribute__((address_space(1))) unsigned int*)g,
      (__attribute__((address_space(3))) unsigned int*)lds, 16, 0, 0);
}

// -------- fp32 -> bf16 conversion (regions 0-4) + RoPE tables (region 5) --------
__global__ __launch_bounds__(256) void cvt_all(
    const float* __restrict__ x, const float* __restrict__ wq,
    const float* __restrict__ wk, const float* __restrict__ wv,
    const float* __restrict__ wo,
    unsigned short* __restrict__ xb, unsigned short* __restrict__ wqkv,
    unsigned short* __restrict__ wob,
    float* __restrict__ ct, float* __restrict__ st) {
  int r = blockIdx.y;
  if (r == 5) {  // RoPE tables: ct/st[s*64+j] = cos/sin(s * 10000^(-j/64))
    int id = blockIdx.x * 256 + threadIdx.x;
    if (id < 131072) {
      int s = id >> 6, j = id & 63;
      float inv = __powf(10000.0f, -(float)j * (1.0f / 64.0f));
      float a = (float)s * inv;
      ct[id] = __cosf(a);
      st[id] = __sinf(a);
    }
    return;
  }
  size_t i = ((size_t)blockIdx.x * 256 + threadIdx.x) * 8;
  const float* src; unsigned short* dst; size_t n;
  if (r == 0)      { src = x;  dst = xb;             n = 8388608; }
  else if (r == 1) { src = wq; dst = wqkv;           n = 4194304; }
  else if (r == 2) { src = wk; dst = wqkv + 4194304; n = 4194304; }
  else if (r == 3) { src = wv; dst = wqkv + 8388608; n = 4194304; }
  else             { src = wo; dst = wob;            n = 4194304; }
  if (i >= n) return;
  float4 a = *(const float4*)(src + i);
  float4 b = *(const float4*)(src + i + 4);
  u16x8v o;
  o[0] = f2bf(a.x); o[1] = f2bf(a.y); o[2] = f2bf(a.z); o[3] = f2bf(a.w);
  o[4] = f2bf(b.x); o[5] = f2bf(b.y); o[6] = f2bf(b.z); o[7] = f2bf(b.w);
  *(u16x8v*)(dst + i) = o;
}

// ---------------- gemm_qk: 256x256x32, 4-deep ring (128KB), grid 16x16=256 ----------------
__global__ __launch_bounds__(512, 2) void gemm_qk(
    const unsigned short* __restrict__ A, const unsigned short* __restrict__ B,
    unsigned short* __restrict__ Qo, unsigned short* __restrict__ Ko, int Kd) {
  __shared__ unsigned short As[4][128 * 64];   // 4 x 16KB
  __shared__ unsigned short Bs[4][128 * 64];   // 4 x 16KB
  const int t = threadIdx.x;
  const int lane = t & 63, w = t >> 6;
  const int g = lane >> 4, c15 = lane & 15;
  const int wm = w >> 2, wn = w & 3;

  const int chunk = (int)blockIdx.x & 7;
  const int idx = (int)blockIdx.x >> 3;       // 0..31
  const int row = idx & 15;
  const int col = chunk * 2 + (idx >> 4);
  const int brow = row * 256, bcol = col * 256;

  const int l = t >> 3;
  const int lg = (t & 7) ^ (l & 7);
  const unsigned short* srcA = A + (size_t)(brow + l + ((lg >> 2) << 7)) * Kd + (lg & 3) * 8;
  const unsigned short* srcB = B + (size_t)(bcol + l + ((lg >> 2) << 7)) * Kd + (lg & 3) * 8;

  auto stage = [&](int kt) {
    const int buf = kt & 3;
    const unsigned short* a = srcA + kt * 32;
    const unsigned short* b = srcB + kt * 32;
    gld16((char*)As[buf] + t * 16, a);
    gld16((char*)As[buf] + 8192 + t * 16, a + (size_t)64 * Kd);
    gld16((char*)Bs[buf] + t * 16, b);
    gld16((char*)Bs[buf] + 8192 + t * 16, b + (size_t)64 * Kd);
  };

  const int aoff = c15 * 128 + ((((wm << 2) | g) ^ (c15 & 7)) << 4);
  const int boff = ((wn & 1) << 13) + c15 * 128 + (((((wn >> 1) << 2) | g) ^ (c15 & 7)) << 4);

  f32x4 zero4 = {0.f, 0.f, 0.f, 0.f};
  f32x4 acc[8][4];
#pragma unroll
  for (int a_ = 0; a_ < 8; ++a_)
#pragma unroll
    for (int b_ = 0; b_ < 4; ++b_) acc[a_][b_] = zero4;

  const int nk = Kd >> 5;  // 64
  stage(0); stage(1); stage(2);
  asm volatile("s_waitcnt vmcnt(8)" ::: "memory");
  __builtin_amdgcn_s_barrier();

  for (int kt = 0; kt < nk; ++kt) {
    const char* ab = (const char*)As[kt & 3];
    const char* bb = (const char*)Bs[kt & 3];
    bf16x8 bfv[4], af0[4], af1[4];
#pragma unroll
    for (int nj = 0; nj < 4; ++nj) bfv[nj] = *(const bf16x8*)(bb + boff + nj * 2048);
#pragma unroll
    for (int mi = 0; mi < 4; ++mi) af0[mi] = *(const bf16x8*)(ab + aoff + mi * 2048);
    __builtin_amdgcn_sched_barrier(0);
#pragma unroll
    for (int mi = 0; mi < 4; ++mi) af1[mi] = *(const bf16x8*)(ab + aoff + (mi + 4) * 2048);
    if (kt + 3 < nk) stage(kt + 3);
    asm volatile("s_waitcnt lgkmcnt(4)" ::: "memory");
    __builtin_amdgcn_sched_barrier(0);
    __builtin_amdgcn_s_setprio(1);
#pragma unroll
    for (int mi = 0; mi < 4; ++mi)
#pragma unroll
      for (int nj = 0; nj < 4; ++nj)
        acc[mi][nj] = __builtin_amdgcn_mfma_f32_16x16x32_bf16(
            af0[mi], bfv[nj], acc[mi][nj], 0, 0, 0);
    __builtin_amdgcn_s_setprio(0);
    asm volatile("s_waitcnt lgkmcnt(0)" ::: "memory");
    __builtin_amdgcn_sched_barrier(0);
    __builtin_amdgcn_s_setprio(1);
#pragma unroll
    for (int mi = 0; mi < 4; ++mi)
#pragma unroll
      for (int nj = 0; nj < 4; ++nj)
        acc[mi + 4][nj] = __builtin_amdgcn_mfma_f32_16x16x32_bf16(
            af1[mi], bfv[nj], acc[mi + 4][nj], 0, 0, 0);
    __builtin_amdgcn_s_setprio(0);
    if (kt + 3 < nk) {
      asm volatile("s_waitcnt vmcnt(8)" ::: "memory");
    } else if (kt + 2 < nk) {
      asm volatile("s_waitcnt vmcnt(4)" ::: "memory");
    } else if (kt + 1 < nk) {
      asm volatile("s_waitcnt vmcnt(0)" ::: "memory");
    }
    __builtin_amdgcn_s_barrier();
  }

#pragma unroll
  for (int mi = 0; mi < 8; ++mi) {
#pragma unroll
    for (int nj = 0; nj < 4; ++nj) {
      f32x4 v = acc[mi][nj];
      int row0 = brow + wm * 128 + mi * 16 + g * 4;
      int colc = bcol + wn * 64 + nj * 16 + c15;
      int which = colc >> 11;           // 0=Q 1=K
      int hc = colc & 2047;
      int bh = ((row0 >> 11) << 4) + (hc >> 7);
      int d = hc & 127, s0 = row0 & 2047;
      unsigned short* dst =
          (which ? Ko : Qo) + ((size_t)bh * 2048 + s0) * 128 + d;
#pragma unroll
      for (int i2 = 0; i2 < 4; ++i2) dst[(size_t)i2 * 128] = f2bf(v[i2]);
    }
  }
}

// ---------------- gemm_v: 128x256x32, 4-deep ring (96KB), grid 32x8=256 ----------------
__global__ __launch_bounds__(512, 2) void gemm_v(
    const unsigned short* __restrict__ A, const unsigned short* __restrict__ B,
    unsigned short* __restrict__ Vt, int Kd) {
  __shared__ unsigned short As[4][64 * 64];    // 4 x 8KB
  __shared__ unsigned short Bs[4][128 * 64];   // 4 x 16KB
  const int t = threadIdx.x;
  const int lane = t & 63, w = t >> 6;
  const int g = lane >> 4, c15 = lane & 15;
  const int wm = w >> 2, wn = w & 3;

  const int chunk = (int)blockIdx.x & 7;
  const int idx = (int)blockIdx.x >> 3;       // 0..31
  const int row = chunk * 4 + (idx >> 3);
  const int col = idx & 7;
  const int brow = row * 128, bcol = col * 256;

  const int l = t >> 3;
  const int lg = (t & 7) ^ (l & 7);
  const unsigned short* srcA = A + (size_t)(brow + l + ((lg >> 2) << 6)) * Kd + (lg & 3) * 8;
  const unsigned short* srcB = B + (size_t)(bcol + l + ((lg >> 2) << 7)) * Kd + (lg & 3) * 8;

  auto stage = [&](int kt) {
    const int buf = kt & 3;
    const unsigned short* a = srcA + kt * 32;
    const unsigned short* b = srcB + kt * 32;
    gld16((char*)As[buf] + t * 16, a);
    gld16((char*)Bs[buf] + t * 16, b);
    gld16((char*)Bs[buf] + 8192 + t * 16, b + (size_t)64 * Kd);
  };

  const int aoff = c15 * 128 + ((((wm << 2) | g) ^ (c15 & 7)) << 4);
  const int boff = ((wn & 1) << 13) + c15 * 128 + (((((wn >> 1) << 2) | g) ^ (c15 & 7)) << 4);

  f32x4 zero4 = {0.f, 0.f, 0.f, 0.f};
  f32x4 acc[4][4];
#pragma unroll
  for (int a_ = 0; a_ < 4; ++a_)
#pragma unroll
    for (int b_ = 0; b_ < 4; ++b_) acc[a_][b_] = zero4;

  const int nk = Kd >> 5;  // 64
  stage(0); stage(1); stage(2);
  asm volatile("s_waitcnt vmcnt(6)" ::: "memory");
  __builtin_amdgcn_s_barrier();

  for (int kt = 0; kt < nk; ++kt) {
    const char* ab = (const char*)As[kt & 3];
    const char* bb = (const char*)Bs[kt & 3];
    bf16x8 bfv[4], af0[2], af1[2];
#pragma unroll
    for (int nj = 0; nj < 4; ++nj) bfv[nj] = *(const bf16x8*)(bb + boff + nj * 2048);
#pragma unroll
    for (int mi = 0; mi < 2; ++mi) af0[mi] = *(const bf16x8*)(ab + aoff + mi * 2048);
    __builtin_amdgcn_sched_barrier(0);
#pragma unroll
    for (int mi = 0; mi < 2; ++mi) af1[mi] = *(const bf16x8*)(ab + aoff + (mi + 2) * 2048);
    if (kt + 3 < nk) stage(kt + 3);
    asm volatile("s_waitcnt lgkmcnt(2)" ::: "memory");
    __builtin_amdgcn_sched_barrier(0);
    __builtin_amdgcn_s_setprio(1);
#pragma unroll
    for (int mi = 0; mi < 2; ++mi)
#pragma unroll
      for (int nj = 0; nj < 4; ++nj)
        acc[mi][nj] = __builtin_amdgcn_mfma_f32_16x16x32_bf16(
            af0[mi], bfv[nj], acc[mi][nj], 0, 0, 0);
    __builtin_amdgcn_s_setprio(0);
    asm volatile("s_waitcnt lgkmcnt(0)" ::: "memory");
    __builtin_amdgcn_sched_barrier(0);
    __builtin_amdgcn_s_setprio(1);
#pragma unroll
    for (int mi = 0; mi < 2; ++mi)
#pragma unroll
      for (int nj = 0; nj < 4; ++nj)
        acc[mi + 2][nj] = __builtin_amdgcn_mfma_f32_16x16x32_bf16(
            af1[mi], bfv[nj], acc[mi + 2][nj], 0, 0, 0);
    __builtin_amdgcn_s_setprio(0);
    if (kt + 3 < nk) {
      asm volatile("s_waitcnt vmcnt(6)" ::: "memory");
    } else if (kt + 3 == nk) {
      asm volatile("s_waitcnt vmcnt(3)" ::: "memory");
    } else if (kt + 2 == nk) {
      asm volatile("s_waitcnt vmcnt(0)" ::: "memory");
    }
    __builtin_amdgcn_s_barrier();
  }

#pragma unroll
  for (int mi = 0; mi < 4; ++mi) {
#pragma unroll
    for (int nj = 0; nj < 4; ++nj) {
      f32x4 v = acc[mi][nj];
      int row0 = brow + wm * 64 + mi * 16 + g * 4;
      int colc = bcol + wn * 64 + nj * 16 + c15;
      int bh = ((row0 >> 11) << 4) + (colc >> 7);
      int d = colc & 127, s0 = row0 & 2047;
      u16x4v pk;
      pk[0] = f2bf(v[0]); pk[1] = f2bf(v[1]); pk[2] = f2bf(v[2]); pk[3] = f2bf(v[3]);
      *(u16x4v*)(Vt + ((size_t)bh * 128 + d) * 2048 + s0) = pk;
    }
  }
}

// ---------------- 128x128x(BK=64) bf16 GEMM (R2-proven) — out-proj ------
__global__ __launch_bounds__(256) void gemm_bt(
    const unsigned short* __restrict__ A, const unsigned short* __restrict__ B,
    float* __restrict__ C, int N, int Kd) {
  __shared__ unsigned short As[128 * 64];
  __shared__ unsigned short Bs[128 * 64];
  const int t = threadIdx.x;
  const int lane = t & 63, w = t >> 6;
  const int g = lane >> 4, c15 = lane & 15;
  const int wr = w >> 1, wc = w & 1;
  const int brow = blockIdx.y * 128, bcol = blockIdx.x * 128;
  const int srow = t >> 3;
  const int ssl = (t & 7) ^ (srow & 7);
  const unsigned short* pA = A + (size_t)(brow + srow) * Kd + ssl * 8;
  const unsigned short* pB = B + (size_t)(bcol + srow) * Kd + ssl * 8;

  int aoff[4][2], boff[4][2];
#pragma unroll
  for (int mi = 0; mi < 4; ++mi)
#pragma unroll
    for (int kk = 0; kk < 2; ++kk) {
      int arow = wr * 64 + mi * 16 + c15;
      int bcolr = wc * 64 + mi * 16 + c15;
      int p = (kk * 4 + g) ^ (c15 & 7);
      aoff[mi][kk] = arow * 128 + (p << 4);
      boff[mi][kk] = bcolr * 128 + (p << 4);
    }
  f32x4 zero4 = {0.f, 0.f, 0.f, 0.f};
  f32x4 acc[4][4];
#pragma unroll
  for (int a_ = 0; a_ < 4; ++a_)
#pragma unroll
    for (int b_ = 0; b_ < 4; ++b_) acc[a_][b_] = zero4;

  const int nk = Kd >> 6;
  for (int kt = 0; kt < nk; ++kt) {
    const unsigned short* a0 = pA + kt * 64;
    const unsigned short* b0 = pB + kt * 64;
#pragma unroll
    for (int c = 0; c < 4; ++c) {
      gld16((char*)As + c * 4096 + t * 16, a0 + (size_t)c * 32 * Kd);
      gld16((char*)Bs + c * 4096 + t * 16, b0 + (size_t)c * 32 * Kd);
    }
    __syncthreads();
    bf16x8 af[4][2], bfv[4][2];
#pragma unroll
    for (int mi = 0; mi < 4; ++mi)
#pragma unroll
      for (int kk = 0; kk < 2; ++kk) {
        af[mi][kk] = *(const bf16x8*)((const char*)As + aoff[mi][kk]);
        bfv[mi][kk] = *(const bf16x8*)((const char*)Bs + boff[mi][kk]);
      }
#pragma unroll
    for (int mi = 0; mi < 4; ++mi)
#pragma unroll
      for (int nj = 0; nj < 4; ++nj)
#pragma unroll
        for (int kk = 0; kk < 2; ++kk)
          acc[mi][nj] = __builtin_amdgcn_mfma_f32_16x16x32_bf16(
              af[mi][kk], bfv[nj][kk], acc[mi][nj], 0, 0, 0);
    __syncthreads();
  }
#pragma unroll
  for (int mi = 0; mi < 4; ++mi)
#pragma unroll
    for (int nj = 0; nj < 4; ++nj) {
      f32x4 v = acc[mi][nj];
      int row0 = brow + wr * 64 + mi * 16 + g * 4;
      int colc = bcol + wc * 64 + nj * 16 + c15;
#pragma unroll
      for (int i = 0; i < 4; ++i) C[(size_t)(row0 + i) * N + colc] = v[i];
    }
}

// ---------------- RoPE (in-place on bf16 Q,K [BH][S][128]); Q gets 1/sqrt(128) folded ----
__global__ __launch_bounds__(256) void rope_apply(
    unsigned short* __restrict__ Q, unsigned short* __restrict__ K,
    const float* __restrict__ ct, const float* __restrict__ st) {
  int id = blockIdx.x * 256 + threadIdx.x;  // 524288 = 32*2048*8
  int o = id & 7;
  int s = (id >> 3) & 2047;
  int bh = id >> 14;
  size_t base = ((size_t)bh * 2048 + s) * 128 + o * 8;
  u16x8v qlo = *(u16x8v*)(Q + base), qhi = *(u16x8v*)(Q + base + 64);
  u16x8v klo = *(u16x8v*)(K + base), khi = *(u16x8v*)(K + base + 64);
  const float* cp = ct + s * 64 + o * 8;
  const float* sp = st + s * 64 + o * 8;
#pragma unroll
  for (int j = 0; j < 8; ++j) {
    float c = cp[j], sn = sp[j];
    float ql = bf2f(qlo[j]), qh = bf2f(qhi[j]);
    qlo[j] = f2bf((ql * c - qh * sn) * SCALE_Q);
    qhi[j] = f2bf((qh * c + ql * sn) * SCALE_Q);
    float kl = bf2f(klo[j]), kh = bf2f(khi[j]);
    klo[j] = f2bf(kl * c - kh * sn);
    khi[j] = f2bf(kh * c + kl * sn);
  }
  *(u16x8v*)(Q + base) = qlo; *(u16x8v*)(Q + base + 64) = qhi;
  *(u16x8v*)(K + base) = klo; *(u16x8v*)(K + base + 64) = khi;
}

// ---------------- attn_fwd R15: QBLK=128, 4 waves x 32 q-rows (2 Q-frags) --------------
// Each K/V frag read feeds 2 MFMA (frag-read : MFMA = 1:2). Pairs (p,15-p) -> uniform 34
// tiles; grid (bh=32, pair=8)=256, XCD-aligned. Counted-vmcnt dbuf; defer-max (T13).
// LDS 88KB -> 1 block/CU.
__global__ __launch_bounds__(256) void attn_fwd(
    const unsigned short* __restrict__ Qg, const unsigned short* __restrict__ Kg,
    const unsigned short* __restrict__ Vtg, unsigned short* __restrict__ Og) {
  __shared__ unsigned short Ks[2][64 * 128];   // [kv64][d128] 256B rows, swz ^(row&15)
  __shared__ unsigned short Vs[2][128 * 64];   // [d128][kv64] 128B rows, swz ^(row&7)
  __shared__ unsigned short Pl[4][32 * 88];    // per-wave P [32 q][88] (176B rows)
  const int t = threadIdx.x;
  const int lane = t & 63, w = t >> 6;         // w 0..3
  const int g = lane >> 4, c15 = lane & 15;
  const int bh = blockIdx.x;                   // 0..31 -> bid%8 = bh%8 = XCD
  const int pair = blockIdx.y;                 // 0..7
  const int b = bh >> 4, h = bh & 15;

  const int ksrow = t >> 4;                    // 0..15
  const int kssl = (t & 15) ^ (ksrow & 15);
  const unsigned short* kp = Kg + ((size_t)bh * 2048 + ksrow) * 128 + kssl * 8;
  const int vsrow = t >> 3;                    // 0..31
  const int vssl = (t & 7) ^ (vsrow & 7);
  const unsigned short* vp = Vtg + ((size_t)bh * 128 + vsrow) * 2048 + vssl * 8;

  auto stageTile = [&](int buf, int tkv) {     // 8 gld16/thread = 32KB total
#pragma unroll
    for (int c = 0; c < 4; ++c) {
      gld16((char*)Ks[buf] + c * 4096 + t * 16, kp + (size_t)(tkv * 64 + c * 16) * 128);
      gld16((char*)Vs[buf] + c * 4096 + t * 16, vp + (size_t)c * 32 * 2048 + tkv * 64);
    }
  };

  f32x4 zero4 = {0.f, 0.f, 0.f, 0.f};
  f32x4 o[2][8];
  float mrow[2][4], lrow[2][4];
  bf16x8 qf[2][4];

  auto loadQ = [&](int qb) {
#pragma unroll
    for (int f = 0; f < 2; ++f) {
      const unsigned short* qp =
          Qg + ((size_t)bh * 2048 + qb * 128 + f * 64 + w * 16 + c15) * 128 + g * 8;
#pragma unroll
      for (int kf = 0; kf < 4; ++kf) qf[f][kf] = *(const bf16x8*)(qp + kf * 32);
#pragma unroll
      for (int db = 0; db < 8; ++db) o[f][db] = zero4;
#pragma unroll
      for (int i = 0; i < 4; ++i) { mrow[f][i] = -1e30f; lrow[f][i] = 0.f; }
    }
  };

  auto computeTile = [&](int buf, int qb, int tkv) {
    f32x4 sv[2][4];
    __builtin_amdgcn_s_setprio(1);
#pragma unroll
    for (int cb = 0; cb < 4; ++cb) {
      f32x4 z0 = zero4, z1 = zero4;
#pragma unroll
      for (int kf = 0; kf < 4; ++kf) {
        int rowk = cb * 16 + c15;
        int p = (kf * 4 + g) ^ c15;
        bf16x8 kfr = *(const bf16x8*)((const char*)Ks[buf] + rowk * 256 + p * 16);
        z0 = __builtin_amdgcn_mfma_f32_16x16x32_bf16(qf[0][kf], kfr, z0, 0, 0, 0);
        z1 = __builtin_amdgcn_mfma_f32_16x16x32_bf16(qf[1][kf], kfr, z1, 0, 0, 0);
      }
      sv[0][cb] = z0; sv[1][cb] = z1;
    }
    __builtin_amdgcn_s_setprio(0);
    if (tkv >= 2 * qb) {  // diagonal tiles causal mask
#pragma unroll
      for (int f = 0; f < 2; ++f)
#pragma unroll
        for (int cb = 0; cb < 4; ++cb)
#pragma unroll
          for (int i = 0; i < 4; ++i) {
            int colk = tkv * 64 + cb * 16 + c15;
            int rq = qb * 128 + f * 64 + w * 16 + g * 4 + i;
            if (colk > rq) sv[f][cb][i] = -1e30f;
          }
    }
    float pmx[2][4];
#pragma unroll
    for (int f = 0; f < 2; ++f)
#pragma unroll
      for (int i = 0; i < 4; ++i)
        pmx[f][i] = fmaxf(fmaxf(sv[f][0][i], sv[f][1][i]),
                          fmaxf(sv[f][2][i], sv[f][3][i]));
#pragma unroll
    for (int dd = 1; dd < 16; dd <<= 1)
#pragma unroll
      for (int f = 0; f < 2; ++f)
#pragma unroll
        for (int i = 0; i < 4; ++i) pmx[f][i] = fmaxf(pmx[f][i], __shfl_xor(pmx[f][i], dd));
    int grow = 0;
#pragma unroll
    for (int f = 0; f < 2; ++f)
#pragma unroll
      for (int i = 0; i < 4; ++i) grow |= (pmx[f][i] > mrow[f][i] + 8.0f) ? 1 : 0;
    if (__any(grow)) {  // defer-max (T13)
#pragma unroll
      for (int f = 0; f < 2; ++f)
#pragma unroll
        for (int i = 0; i < 4; ++i) {
          float nm = fmaxf(mrow[f][i], pmx[f][i]);
          float sc = __expf(mrow[f][i] - nm);
          mrow[f][i] = nm;
          lrow[f][i] *= sc;
#pragma unroll
          for (int db = 0; db < 8; ++db) o[f][db][i] *= sc;
        }
    }
    float psum[2][4] = {{0.f, 0.f, 0.f, 0.f}, {0.f, 0.f, 0.f, 0.f}};
#pragma unroll
    for (int f = 0; f < 2; ++f)
#pragma unroll
      for (int cb = 0; cb < 4; ++cb)
#pragma unroll
        for (int i = 0; i < 4; ++i) {
          float e = __expf(sv[f][cb][i] - mrow[f][i]);
          sv[f][cb][i] = e;
          psum[f][i] += e;
        }
#pragma unroll
    for (int dd = 1; dd < 16; dd <<= 1)
#pragma unroll
      for (int f = 0; f < 2; ++f)
#pragma unroll
        for (int i = 0; i < 4; ++i) psum[f][i] += __shfl_xor(psum[f][i], dd);
#pragma unroll
    for (int f = 0; f < 2; ++f)
#pragma unroll
      for (int i = 0; i < 4; ++i) lrow[f][i] += psum[f][i];

    // P -> per-wave LDS [32 q][88]; rows 0-15 frag0, 16-31 frag1
    unsigned short* pw = &Pl[w][0];
#pragma unroll
    for (int f = 0; f < 2; ++f)
#pragma unroll
      for (int cb = 0; cb < 4; ++cb)
#pragma unroll
        for (int i = 0; i < 4; ++i)
          pw[(f * 16 + g * 4 + i) * 88 + cb * 16 + c15] = f2bf(sv[f][cb][i]);
    bf16x8 pf[2][2];
#pragma unroll
    for (int f = 0; f < 2; ++f)
#pragma unroll
      for (int kb = 0; kb < 2; ++kb)
        pf[f][kb] =
            *(const bf16x8*)((const char*)pw + (f * 16 + c15) * 176 + kb * 64 + g * 16);

    __builtin_amdgcn_s_setprio(1);
#pragma unroll
    for (int db = 0; db < 8; ++db) {
#pragma unroll
      for (int kb = 0; kb < 2; ++kb) {
        int rowv = db * 16 + c15;
        int p = (kb * 4 + g) ^ (c15 & 7);
        bf16x8 vfr = *(const bf16x8*)((const char*)Vs[buf] + rowv * 128 + p * 16);
        o[0][db] = __builtin_amdgcn_mfma_f32_16x16x32_bf16(pf[0][kb], vfr, o[0][db], 0, 0, 0);
        o[1][db] = __builtin_amdgcn_mfma_f32_16x16x32_bf16(pf[1][kb], vfr, o[1][db], 0, 0, 0);
      }
    }
    __builtin_amdgcn_s_setprio(0);
  };

  auto writeO = [&](int qb) {
#pragma unroll
    for (int f = 0; f < 2; ++f) {
      float linv[4];
#pragma unroll
      for (int i = 0; i < 4; ++i) linv[i] = 1.0f / lrow[f][i];
#pragma unroll
      for (int db = 0; db < 8; ++db)
#pragma unroll
        for (int i = 0; i < 4; ++i) {
          int q = qb * 128 + f * 64 + w * 16 + g * 4 + i;
          Og[((size_t)(b * 2048 + q)) * 2048 + h * 128 + db * 16 + c15] =
              f2bf(o[f][db][i] * linv[i]);
        }
    }
  };

  const int qbA = pair, qbB = 15 - pair;       // 128-row q-blocks
  const int ntA = 2 * qbA + 2, ntB = 2 * qbB + 2;  // 34 tiles total, uniform
  int cur = 0;

  stageTile(0, 0);
  loadQ(qbA);
  for (int tkv = 0; tkv < ntA; ++tkv) {
    if (tkv + 1 < ntA) stageTile(cur ^ 1, tkv + 1);
    else               stageTile(cur ^ 1, 0);          // first tile of half B
    asm volatile("s_waitcnt vmcnt(8)" ::: "memory");   // current buf landed
    __builtin_amdgcn_s_barrier();
    computeTile(cur, qbA, tkv);
    __builtin_amdgcn_s_barrier();                      // close reads of buf[cur]
    cur ^= 1;
  }
  writeO(qbA);
  loadQ(qbB);
  for (int tkv = 0; tkv < ntB; ++tkv) {
    if (tkv + 1 < ntB) {
      stageTile(cur ^ 1, tkv + 1);
      asm volatile("s_waitcnt vmcnt(8)" ::: "memory");
    } else {
      asm volatile("s_waitcnt vmcnt(0)" ::: "memory");
    }
    __builtin_amdgcn_s_barrier();
    computeTile(cur, qbB, tkv);
    __builtin_amdgcn_s_barrier();
    cur ^= 1;
  }
  writeO(qbB);
}

extern "C" void kernel_launch(void* const* d_in, const int* in_sizes, int n_in,
                              void* d_out, int out_size, void* d_ws, size_t ws_size,
                              hipStream_t stream) {
  const float* x  = (const float*)d_in[0];
  const float* Wq = (const float*)d_in[1];
  const float* Wk = (const float*)d_in[2];
  const float* Wv = (const float*)d_in[3];
  const float* Wo = (const float*)d_in[4];
  char* p = (char*)d_ws;
  unsigned short* xb    = (unsigned short*)p;                 // 16 MB (reused as Ao)
  unsigned short* wqkvb = (unsigned short*)(p + 16777216);    // 24 MB
  unsigned short* wob   = (unsigned short*)(p + 41943040);    //  8 MB
  unsigned short* Qb    = (unsigned short*)(p + 50331648);    // 16 MB
  unsigned short* Kb    = (unsigned short*)(p + 67108864);    // 16 MB
  unsigned short* Vt    = (unsigned short*)(p + 83886080);    // 16 MB
  float* ctab           = (float*)(p + 100663296);            // 0.5 MB
  float* stab           = (float*)(p + 101187584);            // 0.5 MB -> end 101711872
  unsigned short* Ao = xb;  // xb dead after QKV gemms

  cvt_all<<<dim3(4096, 6), 256, 0, stream>>>(x, Wq, Wk, Wv, Wo, xb, wqkvb, wob,
                                             ctab, stab);
  gemm_qk<<<256, 512, 0, stream>>>(xb, wqkvb, Qb, Kb, 2048);
  gemm_v<<<256, 512, 0, stream>>>(xb, wqkvb + (size_t)4096 * 2048, Vt, 2048);
  rope_apply<<<2048, 256, 0, stream>>>(Qb, Kb, ctab, stab);
  attn_fwd<<<dim3(32, 8), 256, 0, stream>>>(Qb, Kb, Vt, Ao);
  gemm_bt<<<dim3(16, 32), 256, 0, stream>>>(Ao, wob, (float*)d_out, 2048, 2048);
}

// Round 16
// 284.093 us; speedup vs baseline: 1.0282x; 1.0282x over previous
//
#include <hip/hip_runtime.h>
#include <stdint.h>

// Pipeline: cvt(fp32->bf16, + RoPE tables region)
//   -> gemm_qk: x@[Wq;Wk] (N=4096), 256^2 tiles, grid 256 = one full round
//   -> gemm_v : x@Wv (N=2048), 128x256 tiles, grid 256 = one round
//   -> rope(Q,K)
//   -> attn_fwd R16: QBLK=128 (4 waves x 32 q, 2 Q-frags -> each K/V frag read feeds 2
//      MFMA), grid 512 (heavy half bid<256: p=15..8; light half: p=7..0) -> co-resident
//      heavy+light on one CU = uniform 34 tiles/CU at 8 waves/CU. 70KB LDS: K dbuf +
//      SINGLE-buffered V (stage V(t+1) after post-PV barrier; vmcnt(4) leaves only K(t+1)
//      in flight). XCD-aligned (bid%8 = bh%8). Defer-max (T13).
//   -> gemm_bt out-proj (128^2).

#define SCALE_Q 0.08838834764831845f

typedef short bf16x8 __attribute__((ext_vector_type(8)));
typedef float f32x4 __attribute__((ext_vector_type(4)));
typedef unsigned short u16x4v __attribute__((ext_vector_type(4)));
typedef unsigned short u16x8v __attribute__((ext_vector_type(8)));

__device__ __forceinline__ unsigned short f2bf(float f) {
  unsigned u = __float_as_uint(f);
  return (unsigned short)((u + 0x7FFFu + ((u >> 16) & 1u)) >> 16);  // RNE
}
__device__ __forceinline__ float bf2f(unsigned short h) {
  return __uint_as_float(((unsigned)h) << 16);
}
__device__ __forceinline__ void gld16(void* lds, const void* g) {
  __builtin_amdgcn_global_load_lds(
      (const __attribute__((address_space(1))) unsigned int*)g,
      (__attribute__((address_space(3))) unsigned int*)lds, 16, 0, 0);
}

// -------- fp32 -> bf16 conversion (regions 0-4) + RoPE tables (region 5) --------
__global__ __launch_bounds__(256) void cvt_all(
    const float* __restrict__ x, const float* __restrict__ wq,
    const float* __restrict__ wk, const float* __restrict__ wv,
    const float* __restrict__ wo,
    unsigned short* __restrict__ xb, unsigned short* __restrict__ wqkv,
    unsigned short* __restrict__ wob,
    float* __restrict__ ct, float* __restrict__ st) {
  int r = blockIdx.y;
  if (r == 5) {  // RoPE tables: ct/st[s*64+j] = cos/sin(s * 10000^(-j/64))
    int id = blockIdx.x * 256 + threadIdx.x;
    if (id < 131072) {
      int s = id >> 6, j = id & 63;
      float inv = __powf(10000.0f, -(float)j * (1.0f / 64.0f));
      float a = (float)s * inv;
      ct[id] = __cosf(a);
      st[id] = __sinf(a);
    }
    return;
  }
  size_t i = ((size_t)blockIdx.x * 256 + threadIdx.x) * 8;
  const float* src; unsigned short* dst; size_t n;
  if (r == 0)      { src = x;  dst = xb;             n = 8388608; }
  else if (r == 1) { src = wq; dst = wqkv;           n = 4194304; }
  else if (r == 2) { src = wk; dst = wqkv + 4194304; n = 4194304; }
  else if (r == 3) { src = wv; dst = wqkv + 8388608; n = 4194304; }
  else             { src = wo; dst = wob;            n = 4194304; }
  if (i >= n) return;
  float4 a = *(const float4*)(src + i);
  float4 b = *(const float4*)(src + i + 4);
  u16x8v o;
  o[0] = f2bf(a.x); o[1] = f2bf(a.y); o[2] = f2bf(a.z); o[3] = f2bf(a.w);
  o[4] = f2bf(b.x); o[5] = f2bf(b.y); o[6] = f2bf(b.z); o[7] = f2bf(b.w);
  *(u16x8v*)(dst + i) = o;
}

// ---------------- gemm_qk: 256x256x32, 4-deep ring (128KB), grid 16x16=256 ----------------
__global__ __launch_bounds__(512, 2) void gemm_qk(
    const unsigned short* __restrict__ A, const unsigned short* __restrict__ B,
    unsigned short* __restrict__ Qo, unsigned short* __restrict__ Ko, int Kd) {
  __shared__ unsigned short As[4][128 * 64];   // 4 x 16KB
  __shared__ unsigned short Bs[4][128 * 64];   // 4 x 16KB
  const int t = threadIdx.x;
  const int lane = t & 63, w = t >> 6;
  const int g = lane >> 4, c15 = lane & 15;
  const int wm = w >> 2, wn = w & 3;

  const int chunk = (int)blockIdx.x & 7;
  const int idx = (int)blockIdx.x >> 3;       // 0..31
  const int row = idx & 15;
  const int col = chunk * 2 + (idx >> 4);
  const int brow = row * 256, bcol = col * 256;

  const int l = t >> 3;
  const int lg = (t & 7) ^ (l & 7);
  const unsigned short* srcA = A + (size_t)(brow + l + ((lg >> 2) << 7)) * Kd + (lg & 3) * 8;
  const unsigned short* srcB = B + (size_t)(bcol + l + ((lg >> 2) << 7)) * Kd + (lg & 3) * 8;

  auto stage = [&](int kt) {
    const int buf = kt & 3;
    const unsigned short* a = srcA + kt * 32;
    const unsigned short* b = srcB + kt * 32;
    gld16((char*)As[buf] + t * 16, a);
    gld16((char*)As[buf] + 8192 + t * 16, a + (size_t)64 * Kd);
    gld16((char*)Bs[buf] + t * 16, b);
    gld16((char*)Bs[buf] + 8192 + t * 16, b + (size_t)64 * Kd);
  };

  const int aoff = c15 * 128 + ((((wm << 2) | g) ^ (c15 & 7)) << 4);
  const int boff = ((wn & 1) << 13) + c15 * 128 + (((((wn >> 1) << 2) | g) ^ (c15 & 7)) << 4);

  f32x4 zero4 = {0.f, 0.f, 0.f, 0.f};
  f32x4 acc[8][4];
#pragma unroll
  for (int a_ = 0; a_ < 8; ++a_)
#pragma unroll
    for (int b_ = 0; b_ < 4; ++b_) acc[a_][b_] = zero4;

  const int nk = Kd >> 5;  // 64
  stage(0); stage(1); stage(2);
  asm volatile("s_waitcnt vmcnt(8)" ::: "memory");
  __builtin_amdgcn_s_barrier();

  for (int kt = 0; kt < nk; ++kt) {
    const char* ab = (const char*)As[kt & 3];
    const char* bb = (const char*)Bs[kt & 3];
    bf16x8 bfv[4], af0[4], af1[4];
#pragma unroll
    for (int nj = 0; nj < 4; ++nj) bfv[nj] = *(const bf16x8*)(bb + boff + nj * 2048);
#pragma unroll
    for (int mi = 0; mi < 4; ++mi) af0[mi] = *(const bf16x8*)(ab + aoff + mi * 2048);
    __builtin_amdgcn_sched_barrier(0);
#pragma unroll
    for (int mi = 0; mi < 4; ++mi) af1[mi] = *(const bf16x8*)(ab + aoff + (mi + 4) * 2048);
    if (kt + 3 < nk) stage(kt + 3);
    asm volatile("s_waitcnt lgkmcnt(4)" ::: "memory");
    __builtin_amdgcn_sched_barrier(0);
    __builtin_amdgcn_s_setprio(1);
#pragma unroll
    for (int mi = 0; mi < 4; ++mi)
#pragma unroll
      for (int nj = 0; nj < 4; ++nj)
        acc[mi][nj] = __builtin_amdgcn_mfma_f32_16x16x32_bf16(
            af0[mi], bfv[nj], acc[mi][nj], 0, 0, 0);
    __builtin_amdgcn_s_setprio(0);
    asm volatile("s_waitcnt lgkmcnt(0)" ::: "memory");
    __builtin_amdgcn_sched_barrier(0);
    __builtin_amdgcn_s_setprio(1);
#pragma unroll
    for (int mi = 0; mi < 4; ++mi)
#pragma unroll
      for (int nj = 0; nj < 4; ++nj)
        acc[mi + 4][nj] = __builtin_amdgcn_mfma_f32_16x16x32_bf16(
            af1[mi], bfv[nj], acc[mi + 4][nj], 0, 0, 0);
    __builtin_amdgcn_s_setprio(0);
    if (kt + 3 < nk) {
      asm volatile("s_waitcnt vmcnt(8)" ::: "memory");
    } else if (kt + 2 < nk) {
      asm volatile("s_waitcnt vmcnt(4)" ::: "memory");
    } else if (kt + 1 < nk) {
      asm volatile("s_waitcnt vmcnt(0)" ::: "memory");
    }
    __builtin_amdgcn_s_barrier();
  }

#pragma unroll
  for (int mi = 0; mi < 8; ++mi) {
#pragma unroll
    for (int nj = 0; nj < 4; ++nj) {
      f32x4 v = acc[mi][nj];
      int row0 = brow + wm * 128 + mi * 16 + g * 4;
      int colc = bcol + wn * 64 + nj * 16 + c15;
      int which = colc >> 11;           // 0=Q 1=K
      int hc = colc & 2047;
      int bh = ((row0 >> 11) << 4) + (hc >> 7);
      int d = hc & 127, s0 = row0 & 2047;
      unsigned short* dst =
          (which ? Ko : Qo) + ((size_t)bh * 2048 + s0) * 128 + d;
#pragma unroll
      for (int i2 = 0; i2 < 4; ++i2) dst[(size_t)i2 * 128] = f2bf(v[i2]);
    }
  }
}

// ---------------- gemm_v: 128x256x32, 4-deep ring (96KB), grid 32x8=256 ----------------
__global__ __launch_bounds__(512, 2) void gemm_v(
    const unsigned short* __restrict__ A, const unsigned short* __restrict__ B,
    unsigned short* __restrict__ Vt, int Kd) {
  __shared__ unsigned short As[4][64 * 64];    // 4 x 8KB
  __shared__ unsigned short Bs[4][128 * 64];   // 4 x 16KB
  const int t = threadIdx.x;
  const int lane = t & 63, w = t >> 6;
  const int g = lane >> 4, c15 = lane & 15;
  const int wm = w >> 2, wn = w & 3;

  const int chunk = (int)blockIdx.x & 7;
  const int idx = (int)blockIdx.x >> 3;       // 0..31
  const int row = chunk * 4 + (idx >> 3);
  const int col = idx & 7;
  const int brow = row * 128, bcol = col * 256;

  const int l = t >> 3;
  const int lg = (t & 7) ^ (l & 7);
  const unsigned short* srcA = A + (size_t)(brow + l + ((lg >> 2) << 6)) * Kd + (lg & 3) * 8;
  const unsigned short* srcB = B + (size_t)(bcol + l + ((lg >> 2) << 7)) * Kd + (lg & 3) * 8;

  auto stage = [&](int kt) {
    const int buf = kt & 3;
    const unsigned short* a = srcA + kt * 32;
    const unsigned short* b = srcB + kt * 32;
    gld16((char*)As[buf] + t * 16, a);
    gld16((char*)Bs[buf] + t * 16, b);
    gld16((char*)Bs[buf] + 8192 + t * 16, b + (size_t)64 * Kd);
  };

  const int aoff = c15 * 128 + ((((wm << 2) | g) ^ (c15 & 7)) << 4);
  const int boff = ((wn & 1) << 13) + c15 * 128 + (((((wn >> 1) << 2) | g) ^ (c15 & 7)) << 4);

  f32x4 zero4 = {0.f, 0.f, 0.f, 0.f};
  f32x4 acc[4][4];
#pragma unroll
  for (int a_ = 0; a_ < 4; ++a_)
#pragma unroll
    for (int b_ = 0; b_ < 4; ++b_) acc[a_][b_] = zero4;

  const int nk = Kd >> 5;  // 64
  stage(0); stage(1); stage(2);
  asm volatile("s_waitcnt vmcnt(6)" ::: "memory");
  __builtin_amdgcn_s_barrier();

  for (int kt = 0; kt < nk; ++kt) {
    const char* ab = (const char*)As[kt & 3];
    const char* bb = (const char*)Bs[kt & 3];
    bf16x8 bfv[4], af0[2], af1[2];
#pragma unroll
    for (int nj = 0; nj < 4; ++nj) bfv[nj] = *(const bf16x8*)(bb + boff + nj * 2048);
#pragma unroll
    for (int mi = 0; mi < 2; ++mi) af0[mi] = *(const bf16x8*)(ab + aoff + mi * 2048);
    __builtin_amdgcn_sched_barrier(0);
#pragma unroll
    for (int mi = 0; mi < 2; ++mi) af1[mi] = *(const bf16x8*)(ab + aoff + (mi + 2) * 2048);
    if (kt + 3 < nk) stage(kt + 3);
    asm volatile("s_waitcnt lgkmcnt(2)" ::: "memory");
    __builtin_amdgcn_sched_barrier(0);
    __builtin_amdgcn_s_setprio(1);
#pragma unroll
    for (int mi = 0; mi < 2; ++mi)
#pragma unroll
      for (int nj = 0; nj < 4; ++nj)
        acc[mi][nj] = __builtin_amdgcn_mfma_f32_16x16x32_bf16(
            af0[mi], bfv[nj], acc[mi][nj], 0, 0, 0);
    __builtin_amdgcn_s_setprio(0);
    asm volatile("s_waitcnt lgkmcnt(0)" ::: "memory");
    __builtin_amdgcn_sched_barrier(0);
    __builtin_amdgcn_s_setprio(1);
#pragma unroll
    for (int mi = 0; mi < 2; ++mi)
#pragma unroll
      for (int nj = 0; nj < 4; ++nj)
        acc[mi + 2][nj] = __builtin_amdgcn_mfma_f32_16x16x32_bf16(
            af1[mi], bfv[nj], acc[mi + 2][nj], 0, 0, 0);
    __builtin_amdgcn_s_setprio(0);
    if (kt + 3 < nk) {
      asm volatile("s_waitcnt vmcnt(6)" ::: "memory");
    } else if (kt + 3 == nk) {
      asm volatile("s_waitcnt vmcnt(3)" ::: "memory");
    } else if (kt + 2 == nk) {
      asm volatile("s_waitcnt vmcnt(0)" ::: "memory");
    }
    __builtin_amdgcn_s_barrier();
  }

#pragma unroll
  for (int mi = 0; mi < 4; ++mi) {
#pragma unroll
    for (int nj = 0; nj < 4; ++nj) {
      f32x4 v = acc[mi][nj];
      int row0 = brow + wm * 64 + mi * 16 + g * 4;
      int colc = bcol + wn * 64 + nj * 16 + c15;
      int bh = ((row0 >> 11) << 4) + (colc >> 7);
      int d = colc & 127, s0 = row0 & 2047;
      u16x4v pk;
      pk[0] = f2bf(v[0]); pk[1] = f2bf(v[1]); pk[2] = f2bf(v[2]); pk[3] = f2bf(v[3]);
      *(u16x4v*)(Vt + ((size_t)bh * 128 + d) * 2048 + s0) = pk;
    }
  }
}

// ---------------- 128x128x(BK=64) bf16 GEMM (R2-proven) — out-proj ------
__global__ __launch_bounds__(256) void gemm_bt(
    const unsigned short* __restrict__ A, const unsigned short* __restrict__ B,
    float* __restrict__ C, int N, int Kd) {
  __shared__ unsigned short As[128 * 64];
  __shared__ unsigned short Bs[128 * 64];
  const int t = threadIdx.x;
  const int lane = t & 63, w = t >> 6;
  const int g = lane >> 4, c15 = lane & 15;
  const int wr = w >> 1, wc = w & 1;
  const int brow = blockIdx.y * 128, bcol = blockIdx.x * 128;
  const int srow = t >> 3;
  const int ssl = (t & 7) ^ (srow & 7);
  const unsigned short* pA = A + (size_t)(brow + srow) * Kd + ssl * 8;
  const unsigned short* pB = B + (size_t)(bcol + srow) * Kd + ssl * 8;

  int aoff[4][2], boff[4][2];
#pragma unroll
  for (int mi = 0; mi < 4; ++mi)
#pragma unroll
    for (int kk = 0; kk < 2; ++kk) {
      int arow = wr * 64 + mi * 16 + c15;
      int bcolr = wc * 64 + mi * 16 + c15;
      int p = (kk * 4 + g) ^ (c15 & 7);
      aoff[mi][kk] = arow * 128 + (p << 4);
      boff[mi][kk] = bcolr * 128 + (p << 4);
    }
  f32x4 zero4 = {0.f, 0.f, 0.f, 0.f};
  f32x4 acc[4][4];
#pragma unroll
  for (int a_ = 0; a_ < 4; ++a_)
#pragma unroll
    for (int b_ = 0; b_ < 4; ++b_) acc[a_][b_] = zero4;

  const int nk = Kd >> 6;
  for (int kt = 0; kt < nk; ++kt) {
    const unsigned short* a0 = pA + kt * 64;
    const unsigned short* b0 = pB + kt * 64;
#pragma unroll
    for (int c = 0; c < 4; ++c) {
      gld16((char*)As + c * 4096 + t * 16, a0 + (size_t)c * 32 * Kd);
      gld16((char*)Bs + c * 4096 + t * 16, b0 + (size_t)c * 32 * Kd);
    }
    __syncthreads();
    bf16x8 af[4][2], bfv[4][2];
#pragma unroll
    for (int mi = 0; mi < 4; ++mi)
#pragma unroll
      for (int kk = 0; kk < 2; ++kk) {
        af[mi][kk] = *(const bf16x8*)((const char*)As + aoff[mi][kk]);
        bfv[mi][kk] = *(const bf16x8*)((const char*)Bs + boff[mi][kk]);
      }
#pragma unroll
    for (int mi = 0; mi < 4; ++mi)
#pragma unroll
      for (int nj = 0; nj < 4; ++nj)
#pragma unroll
        for (int kk = 0; kk < 2; ++kk)
          acc[mi][nj] = __builtin_amdgcn_mfma_f32_16x16x32_bf16(
              af[mi][kk], bfv[nj][kk], acc[mi][nj], 0, 0, 0);
    __syncthreads();
  }
#pragma unroll
  for (int mi = 0; mi < 4; ++mi)
#pragma unroll
    for (int nj = 0; nj < 4; ++nj) {
      f32x4 v = acc[mi][nj];
      int row0 = brow + wr * 64 + mi * 16 + g * 4;
      int colc = bcol + wc * 64 + nj * 16 + c15;
#pragma unroll
      for (int i = 0; i < 4; ++i) C[(size_t)(row0 + i) * N + colc] = v[i];
    }
}

// ---------------- RoPE (in-place on bf16 Q,K [BH][S][128]); Q gets 1/sqrt(128) folded ----
__global__ __launch_bounds__(256) void rope_apply(
    unsigned short* __restrict__ Q, unsigned short* __restrict__ K,
    const float* __restrict__ ct, const float* __restrict__ st) {
  int id = blockIdx.x * 256 + threadIdx.x;  // 524288 = 32*2048*8
  int o = id & 7;
  int s = (id >> 3) & 2047;
  int bh = id >> 14;
  size_t base = ((size_t)bh * 2048 + s) * 128 + o * 8;
  u16x8v qlo = *(u16x8v*)(Q + base), qhi = *(u16x8v*)(Q + base + 64);
  u16x8v klo = *(u16x8v*)(K + base), khi = *(u16x8v*)(K + base + 64);
  const float* cp = ct + s * 64 + o * 8;
  const float* sp = st + s * 64 + o * 8;
#pragma unroll
  for (int j = 0; j < 8; ++j) {
    float c = cp[j], sn = sp[j];
    float ql = bf2f(qlo[j]), qh = bf2f(qhi[j]);
    qlo[j] = f2bf((ql * c - qh * sn) * SCALE_Q);
    qhi[j] = f2bf((qh * c + ql * sn) * SCALE_Q);
    float kl = bf2f(klo[j]), kh = bf2f(khi[j]);
    klo[j] = f2bf(kl * c - kh * sn);
    khi[j] = f2bf(kh * c + kl * sn);
  }
  *(u16x8v*)(Q + base) = qlo; *(u16x8v*)(Q + base + 64) = qhi;
  *(u16x8v*)(K + base) = klo; *(u16x8v*)(K + base + 64) = khi;
}

// ---------------- attn_fwd R16: QBLK=128, 4 waves x 32 q (2 frags), 512 blocks ----------
// bid<256 heavy (p=15-pg), bid>=256 light (p=pg); bh = bid%32 -> bid%8 = bh%8 (XCD).
// Round-robin pairs bid & bid+256 on one CU: (2(15-pg)+2)+(2pg+2) = 34 tiles uniform.
// LDS 70KB (K dbuf 32K + V single 16K + P 22K) -> 2 blocks/CU = 8 waves/CU.
// Loop: {stage K(t+1) [4 gld]; vmcnt(4) [K(t),V(t) landed, K(t+1) flying]; barrier;
//        QK+softmax+P+PV; barrier; stage V(t+1) [4 gld, overwrites V(t) - safe]}.
__global__ __launch_bounds__(256, 2) void attn_fwd(
    const unsigned short* __restrict__ Qg, const unsigned short* __restrict__ Kg,
    const unsigned short* __restrict__ Vtg, unsigned short* __restrict__ Og) {
  __shared__ unsigned short Ks[2][64 * 128];   // 2 x 16KB, 256B rows, swz ^(row&15)
  __shared__ unsigned short Vs[128 * 64];      // 16KB single buf, 128B rows, swz ^(row&7)
  __shared__ unsigned short Pl[4][32 * 88];    // 22KB: per-wave P [32 q][88] (176B rows)
  const int t = threadIdx.x;
  const int lane = t & 63, w = t >> 6;         // w 0..3
  const int g = lane >> 4, c15 = lane & 15;
  const int bid = (int)blockIdx.x;
  const int half = bid >> 8;                   // 0 = heavy, dispatched first
  const int idx = bid & 255;
  const int bh = idx & 31;                     // bid%8 = bh%8 = XCD
  const int pg = idx >> 5;                     // 0..7
  const int p = half ? pg : 15 - pg;           // q-block (128 rows)
  const int b = bh >> 4, h = bh & 15;
  const int nt = 2 * p + 2;

  const int ksrow = t >> 4;                    // 0..15
  const int kssl = (t & 15) ^ (ksrow & 15);
  const unsigned short* kp = Kg + ((size_t)bh * 2048 + ksrow) * 128 + kssl * 8;
  const int vsrow = t >> 3;                    // 0..31
  const int vssl = (t & 7) ^ (vsrow & 7);
  const unsigned short* vp = Vtg + ((size_t)bh * 128 + vsrow) * 2048 + vssl * 8;

  auto stageK = [&](int tkv) {                 // 4 gld16/thread = 16KB
#pragma unroll
    for (int c = 0; c < 4; ++c)
      gld16((char*)Ks[tkv & 1] + c * 4096 + t * 16,
            kp + (size_t)(tkv * 64 + c * 16) * 128);
  };
  auto stageV = [&](int tkv) {                 // 4 gld16/thread = 16KB
#pragma unroll
    for (int c = 0; c < 4; ++c)
      gld16((char*)Vs + c * 4096 + t * 16, vp + (size_t)c * 32 * 2048 + tkv * 64);
  };

  f32x4 zero4 = {0.f, 0.f, 0.f, 0.f};
  f32x4 o[2][8];
  float mrow[2][4], lrow[2][4];
  bf16x8 qf[2][4];

  // load Q (2 frags x 4), init state — issued before prologue vmcnt(0)
#pragma unroll
  for (int f = 0; f < 2; ++f) {
    const unsigned short* qp =
        Qg + ((size_t)bh * 2048 + p * 128 + f * 64 + w * 16 + c15) * 128 + g * 8;
#pragma unroll
    for (int kf = 0; kf < 4; ++kf) qf[f][kf] = *(const bf16x8*)(qp + kf * 32);
#pragma unroll
    for (int db = 0; db < 8; ++db) o[f][db] = zero4;
#pragma unroll
    for (int i = 0; i < 4; ++i) { mrow[f][i] = -1e30f; lrow[f][i] = 0.f; }
  }

  auto computeTile = [&](int tkv) {
    const char* kb = (const char*)Ks[tkv & 1];
    f32x4 sv[2][4];
    __builtin_amdgcn_s_setprio(1);
#pragma unroll
    for (int cb = 0; cb < 4; ++cb) {
      f32x4 z0 = zero4, z1 = zero4;
#pragma unroll
      for (int kf = 0; kf < 4; ++kf) {
        int rowk = cb * 16 + c15;
        int pp = (kf * 4 + g) ^ c15;
        bf16x8 kfr = *(const bf16x8*)(kb + rowk * 256 + pp * 16);
        z0 = __builtin_amdgcn_mfma_f32_16x16x32_bf16(qf[0][kf], kfr, z0, 0, 0, 0);
        z1 = __builtin_amdgcn_mfma_f32_16x16x32_bf16(qf[1][kf], kfr, z1, 0, 0, 0);
      }
      sv[0][cb] = z0; sv[1][cb] = z1;
    }
    __builtin_amdgcn_s_setprio(0);
    if (tkv >= 2 * p) {  // diagonal tiles causal mask
#pragma unroll
      for (int f = 0; f < 2; ++f)
#pragma unroll
        for (int cb = 0; cb < 4; ++cb)
#pragma unroll
          for (int i = 0; i < 4; ++i) {
            int colk = tkv * 64 + cb * 16 + c15;
            int rq = p * 128 + f * 64 + w * 16 + g * 4 + i;
            if (colk > rq) sv[f][cb][i] = -1e30f;
          }
    }
    float pmx[2][4];
#pragma unroll
    for (int f = 0; f < 2; ++f)
#pragma unroll
      for (int i = 0; i < 4; ++i)
        pmx[f][i] = fmaxf(fmaxf(sv[f][0][i], sv[f][1][i]),
                          fmaxf(sv[f][2][i], sv[f][3][i]));
#pragma unroll
    for (int dd = 1; dd < 16; dd <<= 1)
#pragma unroll
      for (int f = 0; f < 2; ++f)
#pragma unroll
        for (int i = 0; i < 4; ++i)
          pmx[f][i] = fmaxf(pmx[f][i], __shfl_xor(pmx[f][i], dd));
    int grow = 0;
#pragma unroll
    for (int f = 0; f < 2; ++f)
#pragma unroll
      for (int i = 0; i < 4; ++i) grow |= (pmx[f][i] > mrow[f][i] + 8.0f) ? 1 : 0;
    if (__any(grow)) {  // defer-max (T13)
#pragma unroll
      for (int f = 0; f < 2; ++f)
#pragma unroll
        for (int i = 0; i < 4; ++i) {
          float nm = fmaxf(mrow[f][i], pmx[f][i]);
          float sc = __expf(mrow[f][i] - nm);
          mrow[f][i] = nm;
          lrow[f][i] *= sc;
#pragma unroll
          for (int db = 0; db < 8; ++db) o[f][db][i] *= sc;
        }
    }
    float psum[2][4] = {{0.f, 0.f, 0.f, 0.f}, {0.f, 0.f, 0.f, 0.f}};
#pragma unroll
    for (int f = 0; f < 2; ++f)
#pragma unroll
      for (int cb = 0; cb < 4; ++cb)
#pragma unroll
        for (int i = 0; i < 4; ++i) {
          float e = __expf(sv[f][cb][i] - mrow[f][i]);
          sv[f][cb][i] = e;
          psum[f][i] += e;
        }
#pragma unroll
    for (int dd = 1; dd < 16; dd <<= 1)
#pragma unroll
      for (int f = 0; f < 2; ++f)
#pragma unroll
        for (int i = 0; i < 4; ++i) psum[f][i] += __shfl_xor(psum[f][i], dd);
#pragma unroll
    for (int f = 0; f < 2; ++f)
#pragma unroll
      for (int i = 0; i < 4; ++i) lrow[f][i] += psum[f][i];

    // P -> per-wave LDS [32 q][88]: rows 0-15 frag0, 16-31 frag1 (2-way banks max)
    unsigned short* pw = &Pl[w][0];
#pragma unroll
    for (int f = 0; f < 2; ++f)
#pragma unroll
      for (int cb = 0; cb < 4; ++cb)
#pragma unroll
        for (int i = 0; i < 4; ++i)
          pw[(f * 16 + g * 4 + i) * 88 + cb * 16 + c15] = f2bf(sv[f][cb][i]);
    bf16x8 pf[2][2];
#pragma unroll
    for (int f = 0; f < 2; ++f)
#pragma unroll
      for (int kb2 = 0; kb2 < 2; ++kb2)
        pf[f][kb2] =
            *(const bf16x8*)((const char*)pw + (f * 16 + c15) * 176 + kb2 * 64 + g * 16);

    // PV: each V frag read feeds both output frags (1 read : 2 MFMA)
    __builtin_amdgcn_s_setprio(1);
#pragma unroll
    for (int db = 0; db < 8; ++db) {
#pragma unroll
      for (int kb2 = 0; kb2 < 2; ++kb2) {
        int rowv = db * 16 + c15;
        int pp = (kb2 * 4 + g) ^ (c15 & 7);
        bf16x8 vfr = *(const bf16x8*)((const char*)Vs + rowv * 128 + pp * 16);
        o[0][db] = __builtin_amdgcn_mfma_f32_16x16x32_bf16(pf[0][kb2], vfr, o[0][db], 0, 0, 0);
        o[1][db] = __builtin_amdgcn_mfma_f32_16x16x32_bf16(pf[1][kb2], vfr, o[1][db], 0, 0, 0);
      }
    }
    __builtin_amdgcn_s_setprio(0);
  };

  // prologue
  stageK(0); stageV(0);
  asm volatile("s_waitcnt vmcnt(0)" ::: "memory");
  __builtin_amdgcn_s_barrier();

  for (int tk = 0; tk < nt; ++tk) {
    if (tk + 1 < nt) {
      stageK(tk + 1);
      asm volatile("s_waitcnt vmcnt(4)" ::: "memory");  // K(tk),V(tk) landed; K(tk+1) fly
    } else {
      asm volatile("s_waitcnt vmcnt(0)" ::: "memory");
    }
    __builtin_amdgcn_s_barrier();
    computeTile(tk);
    __builtin_amdgcn_s_barrier();                       // all waves done with V(tk), Ks[tk-1 slot]
    if (tk + 1 < nt) stageV(tk + 1);                    // overwrite V — safe after barrier
  }

  // epilogue: O write
#pragma unroll
  for (int f = 0; f < 2; ++f) {
    float linv[4];
#pragma unroll
    for (int i = 0; i < 4; ++i) linv[i] = 1.0f / lrow[f][i];
#pragma unroll
    for (int db = 0; db < 8; ++db)
#pragma unroll
      for (int i = 0; i < 4; ++i) {
        int q = p * 128 + f * 64 + w * 16 + g * 4 + i;
        Og[((size_t)(b * 2048 + q)) * 2048 + h * 128 + db * 16 + c15] =
            f2bf(o[f][db][i] * linv[i]);
      }
  }
}

extern "C" void kernel_launch(void* const* d_in, const int* in_sizes, int n_in,
                              void* d_out, int out_size, void* d_ws, size_t ws_size,
                              hipStream_t stream) {
  const float* x  = (const float*)d_in[0];
  const float* Wq = (const float*)d_in[1];
  const float* Wk = (const float*)d_in[2];
  const float* Wv = (const float*)d_in[3];
  const float* Wo = (const float*)d_in[4];
  char* p = (char*)d_ws;
  unsigned short* xb    = (unsigned short*)p;                 // 16 MB (reused as Ao)
  unsigned short* wqkvb = (unsigned short*)(p + 16777216);    // 24 MB
  unsigned short* wob   = (unsigned short*)(p + 41943040);    //  8 MB
  unsigned short* Qb    = (unsigned short*)(p + 50331648);    // 16 MB
  unsigned short* Kb    = (unsigned short*)(p + 67108864);    // 16 MB
  unsigned short* Vt    = (unsigned short*)(p + 83886080);    // 16 MB
  float* ctab           = (float*)(p + 100663296);            // 0.5 MB
  float* stab           = (float*)(p + 101187584);            // 0.5 MB -> end 101711872
  unsigned short* Ao = xb;  // xb dead after QKV gemms

  cvt_all<<<dim3(4096, 6), 256, 0, stream>>>(x, Wq, Wk, Wv, Wo, xb, wqkvb, wob,
                                             ctab, stab);
  gemm_qk<<<256, 512, 0, stream>>>(xb, wqkvb, Qb, Kb, 2048);
  gemm_v<<<256, 512, 0, stream>>>(xb, wqkvb + (size_t)4096 * 2048, Vt, 2048);
  rope_apply<<<2048, 256, 0, stream>>>(Qb, Kb, ctab, stab);
  attn_fwd<<<512, 256, 0, stream>>>(Qb, Kb, Vt, Ao);
  gemm_bt<<<dim3(16, 32), 256, 0, stream>>>(Ao, wob, (float*)d_out, 2048, 2048);
}

// Round 17
// 265.705 us; speedup vs baseline: 1.0994x; 1.0692x over previous
//
#include <hip/hip_runtime.h>
#include <stdint.h>

// Pipeline: cvt(fp32->bf16, + RoPE tables)
//   -> gemm_qk: x@[Wq;Wk] -> raw Q,K [BH][S][128] (grid 256 = one round)
//   -> gemm_v : x@Wv -> V^T [BH][128][S] (grid 256 = one round)
//   -> rope_k : K-only in-place RoPE (Q-rope fused into attn loadQ)
//   -> attn_fwd (R14 exact, best measured 99us): QBLK=64, 4 waves, pairs (p,31-p),
//      grid (bh=32,pair=16)=512, 75KB LDS -> 2 blocks/CU, XCD-aligned, counted vmcnt,
//      defer-max; loadQ applies RoPE + 1/sqrt(128) in registers (d-pair = kf^2).
//   -> gemm_o : out-proj on deep 128x256 engine, fp32 epilogue, grid 256 = one round.

#define SCALE_Q 0.08838834764831845f

typedef short bf16x8 __attribute__((ext_vector_type(8)));
typedef float f32x4 __attribute__((ext_vector_type(4)));
typedef unsigned short u16x4v __attribute__((ext_vector_type(4)));
typedef unsigned short u16x8v __attribute__((ext_vector_type(8)));

__device__ __forceinline__ unsigned short f2bf(float f) {
  unsigned u = __float_as_uint(f);
  return (unsigned short)((u + 0x7FFFu + ((u >> 16) & 1u)) >> 16);  // RNE
}
__device__ __forceinline__ float bf2f(unsigned short h) {
  return __uint_as_float(((unsigned)h) << 16);
}
__device__ __forceinline__ void gld16(void* lds, const void* g) {
  __builtin_amdgcn_global_load_lds(
      (const __attribute__((address_space(1))) unsigned int*)g,
      (__attribute__((address_space(3))) unsigned int*)lds, 16, 0, 0);
}

// -------- fp32 -> bf16 conversion (regions 0-4) + RoPE tables (region 5) --------
__global__ __launch_bounds__(256) void cvt_all(
    const float* __restrict__ x, const float* __restrict__ wq,
    const float* __restrict__ wk, const float* __restrict__ wv,
    const float* __restrict__ wo,
    unsigned short* __restrict__ xb, unsigned short* __restrict__ wqkv,
    unsigned short* __restrict__ wob,
    float* __restrict__ ct, float* __restrict__ st) {
  int r = blockIdx.y;
  if (r == 5) {  // ct/st[s*64+j] = cos/sin(s * 10000^(-j/64))
    int id = blockIdx.x * 256 + threadIdx.x;
    if (id < 131072) {
      int s = id >> 6, j = id & 63;
      float inv = __powf(10000.0f, -(float)j * (1.0f / 64.0f));
      float a = (float)s * inv;
      ct[id] = __cosf(a);
      st[id] = __sinf(a);
    }
    return;
  }
  size_t i = ((size_t)blockIdx.x * 256 + threadIdx.x) * 8;
  const float* src; unsigned short* dst; size_t n;
  if (r == 0)      { src = x;  dst = xb;             n = 8388608; }
  else if (r == 1) { src = wq; dst = wqkv;           n = 4194304; }
  else if (r == 2) { src = wk; dst = wqkv + 4194304; n = 4194304; }
  else if (r == 3) { src = wv; dst = wqkv + 8388608; n = 4194304; }
  else             { src = wo; dst = wob;            n = 4194304; }
  if (i >= n) return;
  float4 a = *(const float4*)(src + i);
  float4 b = *(const float4*)(src + i + 4);
  u16x8v o;
  o[0] = f2bf(a.x); o[1] = f2bf(a.y); o[2] = f2bf(a.z); o[3] = f2bf(a.w);
  o[4] = f2bf(b.x); o[5] = f2bf(b.y); o[6] = f2bf(b.z); o[7] = f2bf(b.w);
  *(u16x8v*)(dst + i) = o;
}

// ---------------- gemm_qk: 256x256x32, 4-deep ring (128KB), grid 16x16=256 ----------------
__global__ __launch_bounds__(512, 2) void gemm_qk(
    const unsigned short* __restrict__ A, const unsigned short* __restrict__ B,
    unsigned short* __restrict__ Qo, unsigned short* __restrict__ Ko, int Kd) {
  __shared__ unsigned short As[4][128 * 64];   // 4 x 16KB
  __shared__ unsigned short Bs[4][128 * 64];   // 4 x 16KB
  const int t = threadIdx.x;
  const int lane = t & 63, w = t >> 6;
  const int g = lane >> 4, c15 = lane & 15;
  const int wm = w >> 2, wn = w & 3;

  const int chunk = (int)blockIdx.x & 7;
  const int idx = (int)blockIdx.x >> 3;       // 0..31
  const int row = idx & 15;
  const int col = chunk * 2 + (idx >> 4);
  const int brow = row * 256, bcol = col * 256;

  const int l = t >> 3;
  const int lg = (t & 7) ^ (l & 7);
  const unsigned short* srcA = A + (size_t)(brow + l + ((lg >> 2) << 7)) * Kd + (lg & 3) * 8;
  const unsigned short* srcB = B + (size_t)(bcol + l + ((lg >> 2) << 7)) * Kd + (lg & 3) * 8;

  auto stage = [&](int kt) {
    const int buf = kt & 3;
    const unsigned short* a = srcA + kt * 32;
    const unsigned short* b = srcB + kt * 32;
    gld16((char*)As[buf] + t * 16, a);
    gld16((char*)As[buf] + 8192 + t * 16, a + (size_t)64 * Kd);
    gld16((char*)Bs[buf] + t * 16, b);
    gld16((char*)Bs[buf] + 8192 + t * 16, b + (size_t)64 * Kd);
  };

  const int aoff = c15 * 128 + ((((wm << 2) | g) ^ (c15 & 7)) << 4);
  const int boff = ((wn & 1) << 13) + c15 * 128 + (((((wn >> 1) << 2) | g) ^ (c15 & 7)) << 4);

  f32x4 zero4 = {0.f, 0.f, 0.f, 0.f};
  f32x4 acc[8][4];
#pragma unroll
  for (int a_ = 0; a_ < 8; ++a_)
#pragma unroll
    for (int b_ = 0; b_ < 4; ++b_) acc[a_][b_] = zero4;

  const int nk = Kd >> 5;  // 64
  stage(0); stage(1); stage(2);
  asm volatile("s_waitcnt vmcnt(8)" ::: "memory");
  __builtin_amdgcn_s_barrier();

  for (int kt = 0; kt < nk; ++kt) {
    const char* ab = (const char*)As[kt & 3];
    const char* bb = (const char*)Bs[kt & 3];
    bf16x8 bfv[4], af0[4], af1[4];
#pragma unroll
    for (int nj = 0; nj < 4; ++nj) bfv[nj] = *(const bf16x8*)(bb + boff + nj * 2048);
#pragma unroll
    for (int mi = 0; mi < 4; ++mi) af0[mi] = *(const bf16x8*)(ab + aoff + mi * 2048);
    __builtin_amdgcn_sched_barrier(0);
#pragma unroll
    for (int mi = 0; mi < 4; ++mi) af1[mi] = *(const bf16x8*)(ab + aoff + (mi + 4) * 2048);
    if (kt + 3 < nk) stage(kt + 3);
    asm volatile("s_waitcnt lgkmcnt(4)" ::: "memory");
    __builtin_amdgcn_sched_barrier(0);
    __builtin_amdgcn_s_setprio(1);
#pragma unroll
    for (int mi = 0; mi < 4; ++mi)
#pragma unroll
      for (int nj = 0; nj < 4; ++nj)
        acc[mi][nj] = __builtin_amdgcn_mfma_f32_16x16x32_bf16(
            af0[mi], bfv[nj], acc[mi][nj], 0, 0, 0);
    __builtin_amdgcn_s_setprio(0);
    asm volatile("s_waitcnt lgkmcnt(0)" ::: "memory");
    __builtin_amdgcn_sched_barrier(0);
    __builtin_amdgcn_s_setprio(1);
#pragma unroll
    for (int mi = 0; mi < 4; ++mi)
#pragma unroll
      for (int nj = 0; nj < 4; ++nj)
        acc[mi + 4][nj] = __builtin_amdgcn_mfma_f32_16x16x32_bf16(
            af1[mi], bfv[nj], acc[mi + 4][nj], 0, 0, 0);
    __builtin_amdgcn_s_setprio(0);
    if (kt + 3 < nk) {
      asm volatile("s_waitcnt vmcnt(8)" ::: "memory");
    } else if (kt + 2 < nk) {
      asm volatile("s_waitcnt vmcnt(4)" ::: "memory");
    } else if (kt + 1 < nk) {
      asm volatile("s_waitcnt vmcnt(0)" ::: "memory");
    }
    __builtin_amdgcn_s_barrier();
  }

#pragma unroll
  for (int mi = 0; mi < 8; ++mi) {
#pragma unroll
    for (int nj = 0; nj < 4; ++nj) {
      f32x4 v = acc[mi][nj];
      int row0 = brow + wm * 128 + mi * 16 + g * 4;
      int colc = bcol + wn * 64 + nj * 16 + c15;
      int which = colc >> 11;           // 0=Q 1=K
      int hc = colc & 2047;
      int bh = ((row0 >> 11) << 4) + (hc >> 7);
      int d = hc & 127, s0 = row0 & 2047;
      unsigned short* dst =
          (which ? Ko : Qo) + ((size_t)bh * 2048 + s0) * 128 + d;
#pragma unroll
      for (int i2 = 0; i2 < 4; ++i2) dst[(size_t)i2 * 128] = f2bf(v[i2]);
    }
  }
}

// ---------------- gemm_v: 128x256x32, 4-deep ring (96KB), grid 32x8=256 ----------------
__global__ __launch_bounds__(512, 2) void gemm_v(
    const unsigned short* __restrict__ A, const unsigned short* __restrict__ B,
    unsigned short* __restrict__ Vt, int Kd) {
  __shared__ unsigned short As[4][64 * 64];    // 4 x 8KB
  __shared__ unsigned short Bs[4][128 * 64];   // 4 x 16KB
  const int t = threadIdx.x;
  const int lane = t & 63, w = t >> 6;
  const int g = lane >> 4, c15 = lane & 15;
  const int wm = w >> 2, wn = w & 3;

  const int chunk = (int)blockIdx.x & 7;
  const int idx = (int)blockIdx.x >> 3;       // 0..31
  const int row = chunk * 4 + (idx >> 3);
  const int col = idx & 7;
  const int brow = row * 128, bcol = col * 256;

  const int l = t >> 3;
  const int lg = (t & 7) ^ (l & 7);
  const unsigned short* srcA = A + (size_t)(brow + l + ((lg >> 2) << 6)) * Kd + (lg & 3) * 8;
  const unsigned short* srcB = B + (size_t)(bcol + l + ((lg >> 2) << 7)) * Kd + (lg & 3) * 8;

  auto stage = [&](int kt) {
    const int buf = kt & 3;
    const unsigned short* a = srcA + kt * 32;
    const unsigned short* b = srcB + kt * 32;
    gld16((char*)As[buf] + t * 16, a);
    gld16((char*)Bs[buf] + t * 16, b);
    gld16((char*)Bs[buf] + 8192 + t * 16, b + (size_t)64 * Kd);
  };

  const int aoff = c15 * 128 + ((((wm << 2) | g) ^ (c15 & 7)) << 4);
  const int boff = ((wn & 1) << 13) + c15 * 128 + (((((wn >> 1) << 2) | g) ^ (c15 & 7)) << 4);

  f32x4 zero4 = {0.f, 0.f, 0.f, 0.f};
  f32x4 acc[4][4];
#pragma unroll
  for (int a_ = 0; a_ < 4; ++a_)
#pragma unroll
    for (int b_ = 0; b_ < 4; ++b_) acc[a_][b_] = zero4;

  const int nk = Kd >> 5;  // 64
  stage(0); stage(1); stage(2);
  asm volatile("s_waitcnt vmcnt(6)" ::: "memory");
  __builtin_amdgcn_s_barrier();

  for (int kt = 0; kt < nk; ++kt) {
    const char* ab = (const char*)As[kt & 3];
    const char* bb = (const char*)Bs[kt & 3];
    bf16x8 bfv[4], af0[2], af1[2];
#pragma unroll
    for (int nj = 0; nj < 4; ++nj) bfv[nj] = *(const bf16x8*)(bb + boff + nj * 2048);
#pragma unroll
    for (int mi = 0; mi < 2; ++mi) af0[mi] = *(const bf16x8*)(ab + aoff + mi * 2048);
    __builtin_amdgcn_sched_barrier(0);
#pragma unroll
    for (int mi = 0; mi < 2; ++mi) af1[mi] = *(const bf16x8*)(ab + aoff + (mi + 2) * 2048);
    if (kt + 3 < nk) stage(kt + 3);
    asm volatile("s_waitcnt lgkmcnt(2)" ::: "memory");
    __builtin_amdgcn_sched_barrier(0);
    __builtin_amdgcn_s_setprio(1);
#pragma unroll
    for (int mi = 0; mi < 2; ++mi)
#pragma unroll
      for (int nj = 0; nj < 4; ++nj)
        acc[mi][nj] = __builtin_amdgcn_mfma_f32_16x16x32_bf16(
            af0[mi], bfv[nj], acc[mi][nj], 0, 0, 0);
    __builtin_amdgcn_s_setprio(0);
    asm volatile("s_waitcnt lgkmcnt(0)" ::: "memory");
    __builtin_amdgcn_sched_barrier(0);
    __builtin_amdgcn_s_setprio(1);
#pragma unroll
    for (int mi = 0; mi < 2; ++mi)
#pragma unroll
      for (int nj = 0; nj < 4; ++nj)
        acc[mi + 2][nj] = __builtin_amdgcn_mfma_f32_16x16x32_bf16(
            af1[mi], bfv[nj], acc[mi + 2][nj], 0, 0, 0);
    __builtin_amdgcn_s_setprio(0);
    if (kt + 3 < nk) {
      asm volatile("s_waitcnt vmcnt(6)" ::: "memory");
    } else if (kt + 3 == nk) {
      asm volatile("s_waitcnt vmcnt(3)" ::: "memory");
    } else if (kt + 2 == nk) {
      asm volatile("s_waitcnt vmcnt(0)" ::: "memory");
    }
    __builtin_amdgcn_s_barrier();
  }

#pragma unroll
  for (int mi = 0; mi < 4; ++mi) {
#pragma unroll
    for (int nj = 0; nj < 4; ++nj) {
      f32x4 v = acc[mi][nj];
      int row0 = brow + wm * 64 + mi * 16 + g * 4;
      int colc = bcol + wn * 64 + nj * 16 + c15;
      int bh = ((row0 >> 11) << 4) + (colc >> 7);
      int d = colc & 127, s0 = row0 & 2047;
      u16x4v pk;
      pk[0] = f2bf(v[0]); pk[1] = f2bf(v[1]); pk[2] = f2bf(v[2]); pk[3] = f2bf(v[3]);
      *(u16x4v*)(Vt + ((size_t)bh * 128 + d) * 2048 + s0) = pk;
    }
  }
}

// ---------------- gemm_o: out-proj, 128x256x32 deep ring, fp32 epilogue, grid 256 -------
__global__ __launch_bounds__(512, 2) void gemm_o(
    const unsigned short* __restrict__ A, const unsigned short* __restrict__ B,
    float* __restrict__ C, int N, int Kd) {
  __shared__ unsigned short As[4][64 * 64];    // 4 x 8KB
  __shared__ unsigned short Bs[4][128 * 64];   // 4 x 16KB
  const int t = threadIdx.x;
  const int lane = t & 63, w = t >> 6;
  const int g = lane >> 4, c15 = lane & 15;
  const int wm = w >> 2, wn = w & 3;

  const int chunk = (int)blockIdx.x & 7;
  const int idx = (int)blockIdx.x >> 3;       // 0..31
  const int row = chunk * 4 + (idx >> 3);
  const int col = idx & 7;
  const int brow = row * 128, bcol = col * 256;

  const int l = t >> 3;
  const int lg = (t & 7) ^ (l & 7);
  const unsigned short* srcA = A + (size_t)(brow + l + ((lg >> 2) << 6)) * Kd + (lg & 3) * 8;
  const unsigned short* srcB = B + (size_t)(bcol + l + ((lg >> 2) << 7)) * Kd + (lg & 3) * 8;

  auto stage = [&](int kt) {
    const int buf = kt & 3;
    const unsigned short* a = srcA + kt * 32;
    const unsigned short* b = srcB + kt * 32;
    gld16((char*)As[buf] + t * 16, a);
    gld16((char*)Bs[buf] + t * 16, b);
    gld16((char*)Bs[buf] + 8192 + t * 16, b + (size_t)64 * Kd);
  };

  const int aoff = c15 * 128 + ((((wm << 2) | g) ^ (c15 & 7)) << 4);
  const int boff = ((wn & 1) << 13) + c15 * 128 + (((((wn >> 1) << 2) | g) ^ (c15 & 7)) << 4);

  f32x4 zero4 = {0.f, 0.f, 0.f, 0.f};
  f32x4 acc[4][4];
#pragma unroll
  for (int a_ = 0; a_ < 4; ++a_)
#pragma unroll
    for (int b_ = 0; b_ < 4; ++b_) acc[a_][b_] = zero4;

  const int nk = Kd >> 5;  // 64
  stage(0); stage(1); stage(2);
  asm volatile("s_waitcnt vmcnt(6)" ::: "memory");
  __builtin_amdgcn_s_barrier();

  for (int kt = 0; kt < nk; ++kt) {
    const char* ab = (const char*)As[kt & 3];
    const char* bb = (const char*)Bs[kt & 3];
    bf16x8 bfv[4], af0[2], af1[2];
#pragma unroll
    for (int nj = 0; nj < 4; ++nj) bfv[nj] = *(const bf16x8*)(bb + boff + nj * 2048);
#pragma unroll
    for (int mi = 0; mi < 2; ++mi) af0[mi] = *(const bf16x8*)(ab + aoff + mi * 2048);
    __builtin_amdgcn_sched_barrier(0);
#pragma unroll
    for (int mi = 0; mi < 2; ++mi) af1[mi] = *(const bf16x8*)(ab + aoff + (mi + 2) * 2048);
    if (kt + 3 < nk) stage(kt + 3);
    asm volatile("s_waitcnt lgkmcnt(2)" ::: "memory");
    __builtin_amdgcn_sched_barrier(0);
    __builtin_amdgcn_s_setprio(1);
#pragma unroll
    for (int mi = 0; mi < 2; ++mi)
#pragma unroll
      for (int nj = 0; nj < 4; ++nj)
        acc[mi][nj] = __builtin_amdgcn_mfma_f32_16x16x32_bf16(
            af0[mi], bfv[nj], acc[mi][nj], 0, 0, 0);
    __builtin_amdgcn_s_setprio(0);
    asm volatile("s_waitcnt lgkmcnt(0)" ::: "memory");
    __builtin_amdgcn_sched_barrier(0);
    __builtin_amdgcn_s_setprio(1);
#pragma unroll
    for (int mi = 0; mi < 2; ++mi)
#pragma unroll
      for (int nj = 0; nj < 4; ++nj)
        acc[mi + 2][nj] = __builtin_amdgcn_mfma_f32_16x16x32_bf16(
            af1[mi], bfv[nj], acc[mi + 2][nj], 0, 0, 0);
    __builtin_amdgcn_s_setprio(0);
    if (kt + 3 < nk) {
      asm volatile("s_waitcnt vmcnt(6)" ::: "memory");
    } else if (kt + 3 == nk) {
      asm volatile("s_waitcnt vmcnt(3)" ::: "memory");
    } else if (kt + 2 == nk) {
      asm volatile("s_waitcnt vmcnt(0)" ::: "memory");
    }
    __builtin_amdgcn_s_barrier();
  }

#pragma unroll
  for (int mi = 0; mi < 4; ++mi) {
#pragma unroll
    for (int nj = 0; nj < 4; ++nj) {
      f32x4 v = acc[mi][nj];
      int row0 = brow + wm * 64 + mi * 16 + g * 4;
      int colc = bcol + wn * 64 + nj * 16 + c15;
#pragma unroll
      for (int i = 0; i < 4; ++i) C[(size_t)(row0 + i) * N + colc] = v[i];
    }
  }
}

// ---------------- rope_k: K-only in-place RoPE on bf16 [BH][S][128] ----------------
__global__ __launch_bounds__(256) void rope_k(
    unsigned short* __restrict__ K,
    const float* __restrict__ ct, const float* __restrict__ st) {
  int id = blockIdx.x * 256 + threadIdx.x;  // 524288 = 32*2048*8
  int o = id & 7;
  int s = (id >> 3) & 2047;
  int bh = id >> 14;
  size_t base = ((size_t)bh * 2048 + s) * 128 + o * 8;
  u16x8v klo = *(u16x8v*)(K + base), khi = *(u16x8v*)(K + base + 64);
  const float* cp = ct + s * 64 + o * 8;
  const float* sp = st + s * 64 + o * 8;
#pragma unroll
  for (int j = 0; j < 8; ++j) {
    float c = cp[j], sn = sp[j];
    float kl = bf2f(klo[j]), kh = bf2f(khi[j]);
    klo[j] = f2bf(kl * c - kh * sn);
    khi[j] = f2bf(kh * c + kl * sn);
  }
  *(u16x8v*)(K + base) = klo; *(u16x8v*)(K + base + 64) = khi;
}

// ---------------- attn_fwd (R14 exact, + Q-rope fused in loadQ) -------------------------
// QBLK=64 (4 waves x 16 q), KVB=64, pairs p & 31-p (uniform 33 tiles), grid (bh=32,
// pair=16)=512 blocks, 75KB LDS -> 2 blocks/CU; bid%8 = bh%8 (XCD-aligned).
// Counted-vmcnt dbuf: {stage(next) 8 gld16; vmcnt(8); barrier; compute; barrier}.
// Defer-max (T13). loadQ: RoPE rotation is register-local (d-pair = kf^2) + SCALE_Q.
__global__ __launch_bounds__(256, 2) void attn_fwd(
    const unsigned short* __restrict__ Qg, const unsigned short* __restrict__ Kg,
    const unsigned short* __restrict__ Vtg, unsigned short* __restrict__ Og,
    const float* __restrict__ ctab, const float* __restrict__ stab) {
  __shared__ unsigned short Ks[2][64 * 128];   // [kv64][d128] 256B rows, swz ^(row&15)
  __shared__ unsigned short Vs[2][128 * 64];   // [d128][kv64] 128B rows, swz ^(row&7)
  __shared__ unsigned short Pl[4][16 * 88];    // per-wave P buffer
  const int t = threadIdx.x;
  const int lane = t & 63, w = t >> 6;         // w 0..3
  const int g = lane >> 4, c15 = lane & 15;
  const int bh = blockIdx.x;                   // 0..31 -> bid%8 = bh%8 = XCD
  const int pair = blockIdx.y;                 // 0..15
  const int b = bh >> 4, h = bh & 15;

  const int ksrow = t >> 4;                    // 0..15
  const int kssl = (t & 15) ^ (ksrow & 15);
  const unsigned short* kp = Kg + ((size_t)bh * 2048 + ksrow) * 128 + kssl * 8;
  const int vsrow = t >> 3;                    // 0..31
  const int vssl = (t & 7) ^ (vsrow & 7);
  const unsigned short* vp = Vtg + ((size_t)bh * 128 + vsrow) * 2048 + vssl * 8;

  auto stageTile = [&](int buf, int tkv) {     // 8 gld16/thread = 32KB total
#pragma unroll
    for (int c = 0; c < 4; ++c) {
      gld16((char*)Ks[buf] + c * 4096 + t * 16, kp + (size_t)(tkv * 64 + c * 16) * 128);
      gld16((char*)Vs[buf] + c * 4096 + t * 16, vp + (size_t)c * 32 * 2048 + tkv * 64);
    }
  };

  f32x4 zero4 = {0.f, 0.f, 0.f, 0.f};
  f32x4 o[8];
  float mrow[4], lrow[4];
  bf16x8 qf[4];

  auto loadQ = [&](int qb) {
    const int s = qb * 64 + w * 16 + c15;      // this thread's q row
    const unsigned short* qp = Qg + ((size_t)bh * 2048 + s) * 128 + g * 8;
    bf16x8 raw[4];
#pragma unroll
    for (int kf = 0; kf < 4; ++kf) raw[kf] = *(const bf16x8*)(qp + kf * 32);
    // RoPE: d = g*8 + kf*32 + j; pair (d, d+64) = (kf, kf^2); table idx = d%64
    float c0[8], s0v[8], c1[8], s1v[8];
    const float* cb = ctab + s * 64 + g * 8;
    const float* sb = stab + s * 64 + g * 8;
    *(float4*)&c0[0] = *(const float4*)(cb);      *(float4*)&c0[4] = *(const float4*)(cb + 4);
    *(float4*)&c1[0] = *(const float4*)(cb + 32); *(float4*)&c1[4] = *(const float4*)(cb + 36);
    *(float4*)&s0v[0] = *(const float4*)(sb);      *(float4*)&s0v[4] = *(const float4*)(sb + 4);
    *(float4*)&s1v[0] = *(const float4*)(sb + 32); *(float4*)&s1v[4] = *(const float4*)(sb + 36);
#pragma unroll
    for (int j = 0; j < 8; ++j) {
      float a0 = bf2f(raw[0][j]), a1 = bf2f(raw[1][j]);
      float a2 = bf2f(raw[2][j]), a3 = bf2f(raw[3][j]);
      qf[0][j] = f2bf((a0 * c0[j] - a2 * s0v[j]) * SCALE_Q);
      qf[1][j] = f2bf((a1 * c1[j] - a3 * s1v[j]) * SCALE_Q);
      qf[2][j] = f2bf((a2 * c0[j] + a0 * s0v[j]) * SCALE_Q);
      qf[3][j] = f2bf((a3 * c1[j] + a1 * s1v[j]) * SCALE_Q);
    }
#pragma unroll
    for (int db = 0; db < 8; ++db) o[db] = zero4;
#pragma unroll
    for (int i = 0; i < 4; ++i) { mrow[i] = -1e30f; lrow[i] = 0.f; }
  };

  auto computeTile = [&](int buf, int qb, int tkv) {
    const int qrow = qb * 64 + w * 16;
    f32x4 sv[4];
    __builtin_amdgcn_s_setprio(1);
#pragma unroll
    for (int cb2 = 0; cb2 < 4; ++cb2) {
      f32x4 z = zero4;
#pragma unroll
      for (int kf = 0; kf < 4; ++kf) {
        int rowk = cb2 * 16 + c15;
        int p = (kf * 4 + g) ^ c15;
        bf16x8 kfr = *(const bf16x8*)((const char*)Ks[buf] + rowk * 256 + p * 16);
        z = __builtin_amdgcn_mfma_f32_16x16x32_bf16(qf[kf], kfr, z, 0, 0, 0);
      }
      sv[cb2] = z;
    }
    __builtin_amdgcn_s_setprio(0);
    if (tkv == qb) {  // diagonal tile causal mask
#pragma unroll
      for (int cb2 = 0; cb2 < 4; ++cb2)
#pragma unroll
        for (int i = 0; i < 4; ++i) {
          int colk = tkv * 64 + cb2 * 16 + c15;
          int rq = qrow + g * 4 + i;
          if (colk > rq) sv[cb2][i] = -1e30f;
        }
    }
    float pmx[4];
#pragma unroll
    for (int i = 0; i < 4; ++i)
      pmx[i] = fmaxf(fmaxf(sv[0][i], sv[1][i]), fmaxf(sv[2][i], sv[3][i]));
#pragma unroll
    for (int dd = 1; dd < 16; dd <<= 1)
#pragma unroll
      for (int i = 0; i < 4; ++i) pmx[i] = fmaxf(pmx[i], __shfl_xor(pmx[i], dd));
    int grow = 0;
#pragma unroll
    for (int i = 0; i < 4; ++i) grow |= (pmx[i] > mrow[i] + 8.0f) ? 1 : 0;
    if (__any(grow)) {  // defer-max (T13)
#pragma unroll
      for (int i = 0; i < 4; ++i) {
        float nm = fmaxf(mrow[i], pmx[i]);
        float sc = __expf(mrow[i] - nm);
        mrow[i] = nm;
        lrow[i] *= sc;
#pragma unroll
        for (int db = 0; db < 8; ++db) o[db][i] *= sc;
      }
    }
    float psum[4] = {0.f, 0.f, 0.f, 0.f};
#pragma unroll
    for (int cb2 = 0; cb2 < 4; ++cb2)
#pragma unroll
      for (int i = 0; i < 4; ++i) {
        float e = __expf(sv[cb2][i] - mrow[i]);
        sv[cb2][i] = e;
        psum[i] += e;
      }
#pragma unroll
    for (int dd = 1; dd < 16; dd <<= 1)
#pragma unroll
      for (int i = 0; i < 4; ++i) psum[i] += __shfl_xor(psum[i], dd);
#pragma unroll
    for (int i = 0; i < 4; ++i) lrow[i] += psum[i];

    unsigned short* pw = &Pl[w][0];
#pragma unroll
    for (int cb2 = 0; cb2 < 4; ++cb2)
#pragma unroll
      for (int i = 0; i < 4; ++i)
        pw[(g * 4 + i) * 88 + cb2 * 16 + c15] = f2bf(sv[cb2][i]);
    bf16x8 pf[2];
#pragma unroll
    for (int kb = 0; kb < 2; ++kb)
      pf[kb] = *(const bf16x8*)((const char*)pw + c15 * 176 + kb * 64 + g * 16);

    __builtin_amdgcn_s_setprio(1);
#pragma unroll
    for (int db = 0; db < 8; ++db) {
#pragma unroll
      for (int kb = 0; kb < 2; ++kb) {
        int rowv = db * 16 + c15;
        int p = (kb * 4 + g) ^ (c15 & 7);
        bf16x8 vfr = *(const bf16x8*)((const char*)Vs[buf] + rowv * 128 + p * 16);
        o[db] = __builtin_amdgcn_mfma_f32_16x16x32_bf16(pf[kb], vfr, o[db], 0, 0, 0);
      }
    }
    __builtin_amdgcn_s_setprio(0);
  };

  auto writeO = [&](int qb) {
    float linv[4];
#pragma unroll
    for (int i = 0; i < 4; ++i) linv[i] = 1.0f / lrow[i];
#pragma unroll
    for (int db = 0; db < 8; ++db)
#pragma unroll
      for (int i = 0; i < 4; ++i) {
        int q = qb * 64 + w * 16 + g * 4 + i;
        Og[((size_t)(b * 2048 + q)) * 2048 + h * 128 + db * 16 + c15] =
            f2bf(o[db][i] * linv[i]);
      }
  };

  const int qbA = pair, qbB = 31 - pair;       // 64-row q-blocks
  const int ntA = qbA + 1, ntB = qbB + 1;      // 33 tiles total, uniform
  int cur = 0;

  stageTile(0, 0);
  loadQ(qbA);
  for (int tkv = 0; tkv < ntA; ++tkv) {
    if (tkv + 1 < ntA) stageTile(cur ^ 1, tkv + 1);
    else               stageTile(cur ^ 1, 0);          // first tile of half B
    asm volatile("s_waitcnt vmcnt(8)" ::: "memory");   // current buf landed
    __builtin_amdgcn_s_barrier();
    computeTile(cur, qbA, tkv);
    __builtin_amdgcn_s_barrier();                      // close reads of buf[cur]
    cur ^= 1;
  }
  writeO(qbA);
  loadQ(qbB);
  for (int tkv = 0; tkv < ntB; ++tkv) {
    if (tkv + 1 < ntB) {
      stageTile(cur ^ 1, tkv + 1);
      asm volatile("s_waitcnt vmcnt(8)" ::: "memory");
    } else {
      asm volatile("s_waitcnt vmcnt(0)" ::: "memory");
    }
    __builtin_amdgcn_s_barrier();
    computeTile(cur, qbB, tkv);
    __builtin_amdgcn_s_barrier();
    cur ^= 1;
  }
  writeO(qbB);
}

extern "C" void kernel_launch(void* const* d_in, const int* in_sizes, int n_in,
                              void* d_out, int out_size, void* d_ws, size_t ws_size,
                              hipStream_t stream) {
  const float* x  = (const float*)d_in[0];
  const float* Wq = (const float*)d_in[1];
  const float* Wk = (const float*)d_in[2];
  const float* Wv = (const float*)d_in[3];
  const float* Wo = (const float*)d_in[4];
  char* p = (char*)d_ws;
  unsigned short* xb    = (unsigned short*)p;                 // 16 MB (reused as Ao)
  unsigned short* wqkvb = (unsigned short*)(p + 16777216);    // 24 MB
  unsigned short* wob   = (unsigned short*)(p + 41943040);    //  8 MB
  unsigned short* Qb    = (unsigned short*)(p + 50331648);    // 16 MB
  unsigned short* Kb    = (unsigned short*)(p + 67108864);    // 16 MB
  unsigned short* Vt    = (unsigned short*)(p + 83886080);    // 16 MB
  float* ctab           = (float*)(p + 100663296);            // 0.5 MB
  float* stab           = (float*)(p + 101187584);            // 0.5 MB -> end 101711872
  unsigned short* Ao = xb;  // xb dead after QKV gemms

  cvt_all<<<dim3(4096, 6), 256, 0, stream>>>(x, Wq, Wk, Wv, Wo, xb, wqkvb, wob,
                                             ctab, stab);
  gemm_qk<<<256, 512, 0, stream>>>(xb, wqkvb, Qb, Kb, 2048);
  gemm_v<<<256, 512, 0, stream>>>(xb, wqkvb + (size_t)4096 * 2048, Vt, 2048);
  rope_k<<<2048, 256, 0, stream>>>(Kb, ctab, stab);
  attn_fwd<<<dim3(32, 16), 256, 0, stream>>>(Qb, Kb, Vt, Ao, ctab, stab);
  gemm_o<<<256, 512, 0, stream>>>(Ao, wob, (float*)d_out, 2048, 2048);
}

// Round 18
// 256.900 us; speedup vs baseline: 1.1370x; 1.0343x over previous
//
#include <hip/hip_runtime.h>
#include <stdint.h>

// Pipeline: cvt(fp32->bf16, + RoPE tables)
//   -> gemm_qk: x@[Wq;Wk] -> Q,K [BH][S][128] with RoPE FUSED IN EPILOGUE
//      (pair col d^64 = same lane, wave w^1 -> 4B/lane LDS exchange through dead ring
//       buffers; Q also scaled by 1/sqrt(128)); grid 256 = one round
//   -> gemm_v : x@Wv -> V^T [BH][128][S] (grid 256 = one round)
//   -> attn_fwd (R14 exact, measured-best 99us): QBLK=64, 4 waves, pairs (p,31-p),
//      grid (bh=32,pair=16)=512, 75KB LDS -> 2 blocks/CU, XCD-aligned, counted vmcnt,
//      defer-max; loadQ = plain 4 frag loads (Q pre-roped+scaled).
//   -> gemm_o : out-proj on deep 128x256 engine, fp32 epilogue, grid 256 = one round.

#define SCALE_Q 0.08838834764831845f

typedef short bf16x8 __attribute__((ext_vector_type(8)));
typedef float f32x4 __attribute__((ext_vector_type(4)));
typedef unsigned short u16x4v __attribute__((ext_vector_type(4)));
typedef unsigned short u16x8v __attribute__((ext_vector_type(8)));

__device__ __forceinline__ unsigned short f2bf(float f) {
  unsigned u = __float_as_uint(f);
  return (unsigned short)((u + 0x7FFFu + ((u >> 16) & 1u)) >> 16);  // RNE
}
__device__ __forceinline__ float bf2f(unsigned short h) {
  return __uint_as_float(((unsigned)h) << 16);
}
__device__ __forceinline__ void gld16(void* lds, const void* g) {
  __builtin_amdgcn_global_load_lds(
      (const __attribute__((address_space(1))) unsigned int*)g,
      (__attribute__((address_space(3))) unsigned int*)lds, 16, 0, 0);
}

// -------- fp32 -> bf16 conversion (regions 0-4) + RoPE tables (region 5) --------
__global__ __launch_bounds__(256) void cvt_all(
    const float* __restrict__ x, const float* __restrict__ wq,
    const float* __restrict__ wk, const float* __restrict__ wv,
    const float* __restrict__ wo,
    unsigned short* __restrict__ xb, unsigned short* __restrict__ wqkv,
    unsigned short* __restrict__ wob,
    float* __restrict__ ct, float* __restrict__ st) {
  int r = blockIdx.y;
  if (r == 5) {  // ct/st[s*64+j] = cos/sin(s * 10000^(-j/64))
    int id = blockIdx.x * 256 + threadIdx.x;
    if (id < 131072) {
      int s = id >> 6, j = id & 63;
      float inv = __powf(10000.0f, -(float)j * (1.0f / 64.0f));
      float a = (float)s * inv;
      ct[id] = __cosf(a);
      st[id] = __sinf(a);
    }
    return;
  }
  size_t i = ((size_t)blockIdx.x * 256 + threadIdx.x) * 8;
  const float* src; unsigned short* dst; size_t n;
  if (r == 0)      { src = x;  dst = xb;             n = 8388608; }
  else if (r == 1) { src = wq; dst = wqkv;           n = 4194304; }
  else if (r == 2) { src = wk; dst = wqkv + 4194304; n = 4194304; }
  else if (r == 3) { src = wv; dst = wqkv + 8388608; n = 4194304; }
  else             { src = wo; dst = wob;            n = 4194304; }
  if (i >= n) return;
  float4 a = *(const float4*)(src + i);
  float4 b = *(const float4*)(src + i + 4);
  u16x8v o;
  o[0] = f2bf(a.x); o[1] = f2bf(a.y); o[2] = f2bf(a.z); o[3] = f2bf(a.w);
  o[4] = f2bf(b.x); o[5] = f2bf(b.y); o[6] = f2bf(b.z); o[7] = f2bf(b.w);
  *(u16x8v*)(dst + i) = o;
}

// ---------------- gemm_qk: 256x256x32, 4-deep ring (128KB), grid 16x16=256 --------------
// Epilogue fuses RoPE: partner of col d is d^64 = same lane, wave w^1 (wn bit0).
// Exchange fp32 acc slices through dead ring LDS (8 waves x 4KB), lgkm-only barriers.
__global__ __launch_bounds__(512, 2) void gemm_qk(
    const unsigned short* __restrict__ A, const unsigned short* __restrict__ B,
    unsigned short* __restrict__ Qo, unsigned short* __restrict__ Ko, int Kd,
    const float* __restrict__ ctab, const float* __restrict__ stab) {
  __shared__ unsigned short As[4][128 * 64];   // 4 x 16KB
  __shared__ unsigned short Bs[4][128 * 64];   // 4 x 16KB
  const int t = threadIdx.x;
  const int lane = t & 63, w = t >> 6;
  const int g = lane >> 4, c15 = lane & 15;
  const int wm = w >> 2, wn = w & 3;

  const int chunk = (int)blockIdx.x & 7;
  const int idx = (int)blockIdx.x >> 3;       // 0..31
  const int row = idx & 15;
  const int col = chunk * 2 + (idx >> 4);
  const int brow = row * 256, bcol = col * 256;

  const int l = t >> 3;
  const int lg = (t & 7) ^ (l & 7);
  const unsigned short* srcA = A + (size_t)(brow + l + ((lg >> 2) << 7)) * Kd + (lg & 3) * 8;
  const unsigned short* srcB = B + (size_t)(bcol + l + ((lg >> 2) << 7)) * Kd + (lg & 3) * 8;

  auto stage = [&](int kt) {
    const int buf = kt & 3;
    const unsigned short* a = srcA + kt * 32;
    const unsigned short* b = srcB + kt * 32;
    gld16((char*)As[buf] + t * 16, a);
    gld16((char*)As[buf] + 8192 + t * 16, a + (size_t)64 * Kd);
    gld16((char*)Bs[buf] + t * 16, b);
    gld16((char*)Bs[buf] + 8192 + t * 16, b + (size_t)64 * Kd);
  };

  const int aoff = c15 * 128 + ((((wm << 2) | g) ^ (c15 & 7)) << 4);
  const int boff = ((wn & 1) << 13) + c15 * 128 + (((((wn >> 1) << 2) | g) ^ (c15 & 7)) << 4);

  f32x4 zero4 = {0.f, 0.f, 0.f, 0.f};
  f32x4 acc[8][4];
#pragma unroll
  for (int a_ = 0; a_ < 8; ++a_)
#pragma unroll
    for (int b_ = 0; b_ < 4; ++b_) acc[a_][b_] = zero4;

  const int nk = Kd >> 5;  // 64
  stage(0); stage(1); stage(2);
  asm volatile("s_waitcnt vmcnt(8)" ::: "memory");
  __builtin_amdgcn_s_barrier();

  for (int kt = 0; kt < nk; ++kt) {
    const char* ab = (const char*)As[kt & 3];
    const char* bb = (const char*)Bs[kt & 3];
    bf16x8 bfv[4], af0[4], af1[4];
#pragma unroll
    for (int nj = 0; nj < 4; ++nj) bfv[nj] = *(const bf16x8*)(bb + boff + nj * 2048);
#pragma unroll
    for (int mi = 0; mi < 4; ++mi) af0[mi] = *(const bf16x8*)(ab + aoff + mi * 2048);
    __builtin_amdgcn_sched_barrier(0);
#pragma unroll
    for (int mi = 0; mi < 4; ++mi) af1[mi] = *(const bf16x8*)(ab + aoff + (mi + 4) * 2048);
    if (kt + 3 < nk) stage(kt + 3);
    asm volatile("s_waitcnt lgkmcnt(4)" ::: "memory");
    __builtin_amdgcn_sched_barrier(0);
    __builtin_amdgcn_s_setprio(1);
#pragma unroll
    for (int mi = 0; mi < 4; ++mi)
#pragma unroll
      for (int nj = 0; nj < 4; ++nj)
        acc[mi][nj] = __builtin_amdgcn_mfma_f32_16x16x32_bf16(
            af0[mi], bfv[nj], acc[mi][nj], 0, 0, 0);
    __builtin_amdgcn_s_setprio(0);
    asm volatile("s_waitcnt lgkmcnt(0)" ::: "memory");
    __builtin_amdgcn_sched_barrier(0);
    __builtin_amdgcn_s_setprio(1);
#pragma unroll
    for (int mi = 0; mi < 4; ++mi)
#pragma unroll
      for (int nj = 0; nj < 4; ++nj)
        acc[mi + 4][nj] = __builtin_amdgcn_mfma_f32_16x16x32_bf16(
            af1[mi], bfv[nj], acc[mi + 4][nj], 0, 0, 0);
    __builtin_amdgcn_s_setprio(0);
    if (kt + 3 < nk) {
      asm volatile("s_waitcnt vmcnt(8)" ::: "memory");
    } else if (kt + 2 < nk) {
      asm volatile("s_waitcnt vmcnt(4)" ::: "memory");
    } else if (kt + 1 < nk) {
      asm volatile("s_waitcnt vmcnt(0)" ::: "memory");
    }
    __builtin_amdgcn_s_barrier();
  }

  // Epilogue with fused RoPE. All main-loop ds_reads retired (lgkm0 before last MFMA,
  // loop ends with barrier) -> ring LDS reusable as fp32 exchange [8 w][4 nj][4 i][64 lane].
  float* xch = (float*)As;
#pragma unroll
  for (int mi = 0; mi < 8; ++mi) {
#pragma unroll
    for (int nj = 0; nj < 4; ++nj)
#pragma unroll
      for (int i = 0; i < 4; ++i)
        xch[w * 1024 + nj * 256 + i * 64 + lane] = acc[mi][nj][i];
    asm volatile("s_waitcnt lgkmcnt(0)" ::: "memory");
    __builtin_amdgcn_s_barrier();               // slice visible to partner wave
    int row0 = brow + wm * 128 + mi * 16 + g * 4;
    int s0 = row0 & 2047;
#pragma unroll
    for (int nj = 0; nj < 4; ++nj) {
      int colc = bcol + wn * 64 + nj * 16 + c15;
      int which = colc >> 11;           // 0=Q 1=K
      int hc = colc & 2047;
      int bh = ((row0 >> 11) << 4) + (hc >> 7);
      int d = hc & 127;
      int j6 = d & 63;
      float sgn = (d & 64) ? 1.0f : -1.0f;   // out_lo = v*c - hi*s ; out_hi = v*c + lo*s
      float scl = which ? 1.0f : SCALE_Q;
      unsigned short* dst = (which ? Ko : Qo) + ((size_t)bh * 2048 + s0) * 128 + d;
#pragma unroll
      for (int i = 0; i < 4; ++i) {
        float c = ctab[(size_t)(s0 + i) * 64 + j6];
        float sn = stab[(size_t)(s0 + i) * 64 + j6];
        float v = acc[mi][nj][i];
        float pv = xch[(w ^ 1) * 1024 + nj * 256 + i * 64 + lane];
        dst[(size_t)i * 128] = f2bf((v * c + sgn * pv * sn) * scl);
      }
    }
    asm volatile("s_waitcnt lgkmcnt(0)" ::: "memory");
    __builtin_amdgcn_s_barrier();               // reads done before next slice overwrite
  }
}

// ---------------- gemm_v: 128x256x32, 4-deep ring (96KB), grid 32x8=256 ----------------
__global__ __launch_bounds__(512, 2) void gemm_v(
    const unsigned short* __restrict__ A, const unsigned short* __restrict__ B,
    unsigned short* __restrict__ Vt, int Kd) {
  __shared__ unsigned short As[4][64 * 64];    // 4 x 8KB
  __shared__ unsigned short Bs[4][128 * 64];   // 4 x 16KB
  const int t = threadIdx.x;
  const int lane = t & 63, w = t >> 6;
  const int g = lane >> 4, c15 = lane & 15;
  const int wm = w >> 2, wn = w & 3;

  const int chunk = (int)blockIdx.x & 7;
  const int idx = (int)blockIdx.x >> 3;       // 0..31
  const int row = chunk * 4 + (idx >> 3);
  const int col = idx & 7;
  const int brow = row * 128, bcol = col * 256;

  const int l = t >> 3;
  const int lg = (t & 7) ^ (l & 7);
  const unsigned short* srcA = A + (size_t)(brow + l + ((lg >> 2) << 6)) * Kd + (lg & 3) * 8;
  const unsigned short* srcB = B + (size_t)(bcol + l + ((lg >> 2) << 7)) * Kd + (lg & 3) * 8;

  auto stage = [&](int kt) {
    const int buf = kt & 3;
    const unsigned short* a = srcA + kt * 32;
    const unsigned short* b = srcB + kt * 32;
    gld16((char*)As[buf] + t * 16, a);
    gld16((char*)Bs[buf] + t * 16, b);
    gld16((char*)Bs[buf] + 8192 + t * 16, b + (size_t)64 * Kd);
  };

  const int aoff = c15 * 128 + ((((wm << 2) | g) ^ (c15 & 7)) << 4);
  const int boff = ((wn & 1) << 13) + c15 * 128 + (((((wn >> 1) << 2) | g) ^ (c15 & 7)) << 4);

  f32x4 zero4 = {0.f, 0.f, 0.f, 0.f};
  f32x4 acc[4][4];
#pragma unroll
  for (int a_ = 0; a_ < 4; ++a_)
#pragma unroll
    for (int b_ = 0; b_ < 4; ++b_) acc[a_][b_] = zero4;

  const int nk = Kd >> 5;  // 64
  stage(0); stage(1); stage(2);
  asm volatile("s_waitcnt vmcnt(6)" ::: "memory");
  __builtin_amdgcn_s_barrier();

  for (int kt = 0; kt < nk; ++kt) {
    const char* ab = (const char*)As[kt & 3];
    const char* bb = (const char*)Bs[kt & 3];
    bf16x8 bfv[4], af0[2], af1[2];
#pragma unroll
    for (int nj = 0; nj < 4; ++nj) bfv[nj] = *(const bf16x8*)(bb + boff + nj * 2048);
#pragma unroll
    for (int mi = 0; mi < 2; ++mi) af0[mi] = *(const bf16x8*)(ab + aoff + mi * 2048);
    __builtin_amdgcn_sched_barrier(0);
#pragma unroll
    for (int mi = 0; mi < 2; ++mi) af1[mi] = *(const bf16x8*)(ab + aoff + (mi + 2) * 2048);
    if (kt + 3 < nk) stage(kt + 3);
    asm volatile("s_waitcnt lgkmcnt(2)" ::: "memory");
    __builtin_amdgcn_sched_barrier(0);
    __builtin_amdgcn_s_setprio(1);
#pragma unroll
    for (int mi = 0; mi < 2; ++mi)
#pragma unroll
      for (int nj = 0; nj < 4; ++nj)
        acc[mi][nj] = __builtin_amdgcn_mfma_f32_16x16x32_bf16(
            af0[mi], bfv[nj], acc[mi][nj], 0, 0, 0);
    __builtin_amdgcn_s_setprio(0);
    asm volatile("s_waitcnt lgkmcnt(0)" ::: "memory");
    __builtin_amdgcn_sched_barrier(0);
    __builtin_amdgcn_s_setprio(1);
#pragma unroll
    for (int mi = 0; mi < 2; ++mi)
#pragma unroll
      for (int nj = 0; nj < 4; ++nj)
        acc[mi + 2][nj] = __builtin_amdgcn_mfma_f32_16x16x32_bf16(
            af1[mi], bfv[nj], acc[mi + 2][nj], 0, 0, 0);
    __builtin_amdgcn_s_setprio(0);
    if (kt + 3 < nk) {
      asm volatile("s_waitcnt vmcnt(6)" ::: "memory");
    } else if (kt + 3 == nk) {
      asm volatile("s_waitcnt vmcnt(3)" ::: "memory");
    } else if (kt + 2 == nk) {
      asm volatile("s_waitcnt vmcnt(0)" ::: "memory");
    }
    __builtin_amdgcn_s_barrier();
  }

#pragma unroll
  for (int mi = 0; mi < 4; ++mi) {
#pragma unroll
    for (int nj = 0; nj < 4; ++nj) {
      f32x4 v = acc[mi][nj];
      int row0 = brow + wm * 64 + mi * 16 + g * 4;
      int colc = bcol + wn * 64 + nj * 16 + c15;
      int bh = ((row0 >> 11) << 4) + (colc >> 7);
      int d = colc & 127, s0 = row0 & 2047;
      u16x4v pk;
      pk[0] = f2bf(v[0]); pk[1] = f2bf(v[1]); pk[2] = f2bf(v[2]); pk[3] = f2bf(v[3]);
      *(u16x4v*)(Vt + ((size_t)bh * 128 + d) * 2048 + s0) = pk;
    }
  }
}

// ---------------- gemm_o: out-proj, 128x256x32 deep ring, fp32 epilogue, grid 256 -------
__global__ __launch_bounds__(512, 2) void gemm_o(
    const unsigned short* __restrict__ A, const unsigned short* __restrict__ B,
    float* __restrict__ C, int N, int Kd) {
  __shared__ unsigned short As[4][64 * 64];    // 4 x 8KB
  __shared__ unsigned short Bs[4][128 * 64];   // 4 x 16KB
  const int t = threadIdx.x;
  const int lane = t & 63, w = t >> 6;
  const int g = lane >> 4, c15 = lane & 15;
  const int wm = w >> 2, wn = w & 3;

  const int chunk = (int)blockIdx.x & 7;
  const int idx = (int)blockIdx.x >> 3;       // 0..31
  const int row = chunk * 4 + (idx >> 3);
  const int col = idx & 7;
  const int brow = row * 128, bcol = col * 256;

  const int l = t >> 3;
  const int lg = (t & 7) ^ (l & 7);
  const unsigned short* srcA = A + (size_t)(brow + l + ((lg >> 2) << 6)) * Kd + (lg & 3) * 8;
  const unsigned short* srcB = B + (size_t)(bcol + l + ((lg >> 2) << 7)) * Kd + (lg & 3) * 8;

  auto stage = [&](int kt) {
    const int buf = kt & 3;
    const unsigned short* a = srcA + kt * 32;
    const unsigned short* b = srcB + kt * 32;
    gld16((char*)As[buf] + t * 16, a);
    gld16((char*)Bs[buf] + t * 16, b);
    gld16((char*)Bs[buf] + 8192 + t * 16, b + (size_t)64 * Kd);
  };

  const int aoff = c15 * 128 + ((((wm << 2) | g) ^ (c15 & 7)) << 4);
  const int boff = ((wn & 1) << 13) + c15 * 128 + (((((wn >> 1) << 2) | g) ^ (c15 & 7)) << 4);

  f32x4 zero4 = {0.f, 0.f, 0.f, 0.f};
  f32x4 acc[4][4];
#pragma unroll
  for (int a_ = 0; a_ < 4; ++a_)
#pragma unroll
    for (int b_ = 0; b_ < 4; ++b_) acc[a_][b_] = zero4;

  const int nk = Kd >> 5;  // 64
  stage(0); stage(1); stage(2);
  asm volatile("s_waitcnt vmcnt(6)" ::: "memory");
  __builtin_amdgcn_s_barrier();

  for (int kt = 0; kt < nk; ++kt) {
    const char* ab = (const char*)As[kt & 3];
    const char* bb = (const char*)Bs[kt & 3];
    bf16x8 bfv[4], af0[2], af1[2];
#pragma unroll
    for (int nj = 0; nj < 4; ++nj) bfv[nj] = *(const bf16x8*)(bb + boff + nj * 2048);
#pragma unroll
    for (int mi = 0; mi < 2; ++mi) af0[mi] = *(const bf16x8*)(ab + aoff + mi * 2048);
    __builtin_amdgcn_sched_barrier(0);
#pragma unroll
    for (int mi = 0; mi < 2; ++mi) af1[mi] = *(const bf16x8*)(ab + aoff + (mi + 2) * 2048);
    if (kt + 3 < nk) stage(kt + 3);
    asm volatile("s_waitcnt lgkmcnt(2)" ::: "memory");
    __builtin_amdgcn_sched_barrier(0);
    __builtin_amdgcn_s_setprio(1);
#pragma unroll
    for (int mi = 0; mi < 2; ++mi)
#pragma unroll
      for (int nj = 0; nj < 4; ++nj)
        acc[mi][nj] = __builtin_amdgcn_mfma_f32_16x16x32_bf16(
            af0[mi], bfv[nj], acc[mi][nj], 0, 0, 0);
    __builtin_amdgcn_s_setprio(0);
    asm volatile("s_waitcnt lgkmcnt(0)" ::: "memory");
    __builtin_amdgcn_sched_barrier(0);
    __builtin_amdgcn_s_setprio(1);
#pragma unroll
    for (int mi = 0; mi < 2; ++mi)
#pragma unroll
      for (int nj = 0; nj < 4; ++nj)
        acc[mi + 2][nj] = __builtin_amdgcn_mfma_f32_16x16x32_bf16(
            af1[mi], bfv[nj], acc[mi + 2][nj], 0, 0, 0);
    __builtin_amdgcn_s_setprio(0);
    if (kt + 3 < nk) {
      asm volatile("s_waitcnt vmcnt(6)" ::: "memory");
    } else if (kt + 3 == nk) {
      asm volatile("s_waitcnt vmcnt(3)" ::: "memory");
    } else if (kt + 2 == nk) {
      asm volatile("s_waitcnt vmcnt(0)" ::: "memory");
    }
    __builtin_amdgcn_s_barrier();
  }

#pragma unroll
  for (int mi = 0; mi < 4; ++mi) {
#pragma unroll
    for (int nj = 0; nj < 4; ++nj) {
      f32x4 v = acc[mi][nj];
      int row0 = brow + wm * 64 + mi * 16 + g * 4;
      int colc = bcol + wn * 64 + nj * 16 + c15;
#pragma unroll
      for (int i = 0; i < 4; ++i) C[(size_t)(row0 + i) * N + colc] = v[i];
    }
  }
}

// ---------------- attn_fwd (R14 exact; Q pre-roped+scaled by gemm_qk epilogue) ----------
// QBLK=64 (4 waves x 16 q), KVB=64, pairs p & 31-p (uniform 33 tiles), grid (bh=32,
// pair=16)=512 blocks, 75KB LDS -> 2 blocks/CU; bid%8 = bh%8 (XCD-aligned).
// Counted-vmcnt dbuf: {stage(next) 8 gld16; vmcnt(8); barrier; compute; barrier}.
// Defer-max (T13).
__global__ __launch_bounds__(256, 2) void attn_fwd(
    const unsigned short* __restrict__ Qg, const unsigned short* __restrict__ Kg,
    const unsigned short* __restrict__ Vtg, unsigned short* __restrict__ Og) {
  __shared__ unsigned short Ks[2][64 * 128];   // [kv64][d128] 256B rows, swz ^(row&15)
  __shared__ unsigned short Vs[2][128 * 64];   // [d128][kv64] 128B rows, swz ^(row&7)
  __shared__ unsigned short Pl[4][16 * 88];    // per-wave P buffer
  const int t = threadIdx.x;
  const int lane = t & 63, w = t >> 6;         // w 0..3
  const int g = lane >> 4, c15 = lane & 15;
  const int bh = blockIdx.x;                   // 0..31 -> bid%8 = bh%8 = XCD
  const int pair = blockIdx.y;                 // 0..15
  const int b = bh >> 4, h = bh & 15;

  const int ksrow = t >> 4;                    // 0..15
  const int kssl = (t & 15) ^ (ksrow & 15);
  const unsigned short* kp = Kg + ((size_t)bh * 2048 + ksrow) * 128 + kssl * 8;
  const int vsrow = t >> 3;                    // 0..31
  const int vssl = (t & 7) ^ (vsrow & 7);
  const unsigned short* vp = Vtg + ((size_t)bh * 128 + vsrow) * 2048 + vssl * 8;

  auto stageTile = [&](int buf, int tkv) {     // 8 gld16/thread = 32KB total
#pragma unroll
    for (int c = 0; c < 4; ++c) {
      gld16((char*)Ks[buf] + c * 4096 + t * 16, kp + (size_t)(tkv * 64 + c * 16) * 128);
      gld16((char*)Vs[buf] + c * 4096 + t * 16, vp + (size_t)c * 32 * 2048 + tkv * 64);
    }
  };

  f32x4 zero4 = {0.f, 0.f, 0.f, 0.f};
  f32x4 o[8];
  float mrow[4], lrow[4];
  bf16x8 qf[4];

  auto loadQ = [&](int qb) {
    const unsigned short* qp =
        Qg + ((size_t)bh * 2048 + qb * 64 + w * 16 + c15) * 128 + g * 8;
#pragma unroll
    for (int kf = 0; kf < 4; ++kf) qf[kf] = *(const bf16x8*)(qp + kf * 32);
#pragma unroll
    for (int db = 0; db < 8; ++db) o[db] = zero4;
#pragma unroll
    for (int i = 0; i < 4; ++i) { mrow[i] = -1e30f; lrow[i] = 0.f; }
  };

  auto computeTile = [&](int buf, int qb, int tkv) {
    const int qrow = qb * 64 + w * 16;
    f32x4 sv[4];
    __builtin_amdgcn_s_setprio(1);
#pragma unroll
    for (int cb2 = 0; cb2 < 4; ++cb2) {
      f32x4 z = zero4;
#pragma unroll
      for (int kf = 0; kf < 4; ++kf) {
        int rowk = cb2 * 16 + c15;
        int p = (kf * 4 + g) ^ c15;
        bf16x8 kfr = *(const bf16x8*)((const char*)Ks[buf] + rowk * 256 + p * 16);
        z = __builtin_amdgcn_mfma_f32_16x16x32_bf16(qf[kf], kfr, z, 0, 0, 0);
      }
      sv[cb2] = z;
    }
    __builtin_amdgcn_s_setprio(0);
    if (tkv == qb) {  // diagonal tile causal mask
#pragma unroll
      for (int cb2 = 0; cb2 < 4; ++cb2)
#pragma unroll
        for (int i = 0; i < 4; ++i) {
          int colk = tkv * 64 + cb2 * 16 + c15;
          int rq = qrow + g * 4 + i;
          if (colk > rq) sv[cb2][i] = -1e30f;
        }
    }
    float pmx[4];
#pragma unroll
    for (int i = 0; i < 4; ++i)
      pmx[i] = fmaxf(fmaxf(sv[0][i], sv[1][i]), fmaxf(sv[2][i], sv[3][i]));
#pragma unroll
    for (int dd = 1; dd < 16; dd <<= 1)
#pragma unroll
      for (int i = 0; i < 4; ++i) pmx[i] = fmaxf(pmx[i], __shfl_xor(pmx[i], dd));
    int grow = 0;
#pragma unroll
    for (int i = 0; i < 4; ++i) grow |= (pmx[i] > mrow[i] + 8.0f) ? 1 : 0;
    if (__any(grow)) {  // defer-max (T13)
#pragma unroll
      for (int i = 0; i < 4; ++i) {
        float nm = fmaxf(mrow[i], pmx[i]);
        float sc = __expf(mrow[i] - nm);
        mrow[i] = nm;
        lrow[i] *= sc;
#pragma unroll
        for (int db = 0; db < 8; ++db) o[db][i] *= sc;
      }
    }
    float psum[4] = {0.f, 0.f, 0.f, 0.f};
#pragma unroll
    for (int cb2 = 0; cb2 < 4; ++cb2)
#pragma unroll
      for (int i = 0; i < 4; ++i) {
        float e = __expf(sv[cb2][i] - mrow[i]);
        sv[cb2][i] = e;
        psum[i] += e;
      }
#pragma unroll
    for (int dd = 1; dd < 16; dd <<= 1)
#pragma unroll
      for (int i = 0; i < 4; ++i) psum[i] += __shfl_xor(psum[i], dd);
#pragma unroll
    for (int i = 0; i < 4; ++i) lrow[i] += psum[i];

    unsigned short* pw = &Pl[w][0];
#pragma unroll
    for (int cb2 = 0; cb2 < 4; ++cb2)
#pragma unroll
      for (int i = 0; i < 4; ++i)
        pw[(g * 4 + i) * 88 + cb2 * 16 + c15] = f2bf(sv[cb2][i]);
    bf16x8 pf[2];
#pragma unroll
    for (int kb = 0; kb < 2; ++kb)
      pf[kb] = *(const bf16x8*)((const char*)pw + c15 * 176 + kb * 64 + g * 16);

    __builtin_amdgcn_s_setprio(1);
#pragma unroll
    for (int db = 0; db < 8; ++db) {
#pragma unroll
      for (int kb = 0; kb < 2; ++kb) {
        int rowv = db * 16 + c15;
        int p = (kb * 4 + g) ^ (c15 & 7);
        bf16x8 vfr = *(const bf16x8*)((const char*)Vs[buf] + rowv * 128 + p * 16);
        o[db] = __builtin_amdgcn_mfma_f32_16x16x32_bf16(pf[kb], vfr, o[db], 0, 0, 0);
      }
    }
    __builtin_amdgcn_s_setprio(0);
  };

  auto writeO = [&](int qb) {
    float linv[4];
#pragma unroll
    for (int i = 0; i < 4; ++i) linv[i] = 1.0f / lrow[i];
#pragma unroll
    for (int db = 0; db < 8; ++db)
#pragma unroll
      for (int i = 0; i < 4; ++i) {
        int q = qb * 64 + w * 16 + g * 4 + i;
        Og[((size_t)(b * 2048 + q)) * 2048 + h * 128 + db * 16 + c15] =
            f2bf(o[db][i] * linv[i]);
      }
  };

  const int qbA = pair, qbB = 31 - pair;       // 64-row q-blocks
  const int ntA = qbA + 1, ntB = qbB + 1;      // 33 tiles total, uniform
  int cur = 0;

  stageTile(0, 0);
  loadQ(qbA);
  for (int tkv = 0; tkv < ntA; ++tkv) {
    if (tkv + 1 < ntA) stageTile(cur ^ 1, tkv + 1);
    else               stageTile(cur ^ 1, 0);          // first tile of half B
    asm volatile("s_waitcnt vmcnt(8)" ::: "memory");   // current buf landed
    __builtin_amdgcn_s_barrier();
    computeTile(cur, qbA, tkv);
    __builtin_amdgcn_s_barrier();                      // close reads of buf[cur]
    cur ^= 1;
  }
  writeO(qbA);
  loadQ(qbB);
  for (int tkv = 0; tkv < ntB; ++tkv) {
    if (tkv + 1 < ntB) {
      stageTile(cur ^ 1, tkv + 1);
      asm volatile("s_waitcnt vmcnt(8)" ::: "memory");
    } else {
      asm volatile("s_waitcnt vmcnt(0)" ::: "memory");
    }
    __builtin_amdgcn_s_barrier();
    computeTile(cur, qbB, tkv);
    __builtin_amdgcn_s_barrier();
    cur ^= 1;
  }
  writeO(qbB);
}

extern "C" void kernel_launch(void* const* d_in, const int* in_sizes, int n_in,
                              void* d_out, int out_size, void* d_ws, size_t ws_size,
                              hipStream_t stream) {
  const float* x  = (const float*)d_in[0];
  const float* Wq = (const float*)d_in[1];
  const float* Wk = (const float*)d_in[2];
  const float* Wv = (const float*)d_in[3];
  const float* Wo = (const float*)d_in[4];
  char* p = (char*)d_ws;
  unsigned short* xb    = (unsigned short*)p;                 // 16 MB (reused as Ao)
  unsigned short* wqkvb = (unsigned short*)(p + 16777216);    // 24 MB
  unsigned short* wob   = (unsigned short*)(p + 41943040);    //  8 MB
  unsigned short* Qb    = (unsigned short*)(p + 50331648);    // 16 MB
  unsigned short* Kb    = (unsigned short*)(p + 67108864);    // 16 MB
  unsigned short* Vt    = (unsigned short*)(p + 83886080);    // 16 MB
  float* ctab           = (float*)(p + 100663296);            // 0.5 MB
  float* stab           = (float*)(p + 101187584);            // 0.5 MB -> end 101711872
  unsigned short* Ao = xb;  // xb dead after QKV gemms

  cvt_all<<<dim3(4096, 6), 256, 0, stream>>>(x, Wq, Wk, Wv, Wo, xb, wqkvb, wob,
                                             ctab, stab);
  gemm_qk<<<256, 512, 0, stream>>>(xb, wqkvb, Qb, Kb, 2048, ctab, stab);
  gemm_v<<<256, 512, 0, stream>>>(xb, wqkvb + (size_t)4096 * 2048, Vt, 2048);
  attn_fwd<<<dim3(32, 16), 256, 0, stream>>>(Qb, Kb, Vt, Ao);
  gemm_o<<<256, 512, 0, stream>>>(Ao, wob, (float*)d_out, 2048, 2048);
}